// Round 1
// baseline (3128.332 us; speedup 1.0000x reference)
//
#include <hip/hip_runtime.h>
#include <hip/hip_bf16.h>
#include <stdint.h>
#include <stddef.h>

typedef __attribute__((ext_vector_type(8))) short short8v;  // 8 bf16 bits = 4 VGPR
typedef __attribute__((ext_vector_type(4))) float f32x4;

__device__ __forceinline__ float bf2f(unsigned short u) {
    return __uint_as_float(((unsigned int)u) << 16);
}
__device__ __forceinline__ unsigned short f2bf(float f) {
    unsigned int x = __float_as_uint(f);
    x += 0x7fffu + ((x >> 16) & 1u);   // RNE
    return (unsigned short)(x >> 16);
}

#define NTOK 8192      // b*n
#define DM   1024
#define NPROJ 3072     // q512 | k512 | v1024 | g1024
#define SEQ  4096
#define NCHUNK 64      // chunks per sequence (4096/64)

// ---------------- elementwise / conversion ----------------
__global__ void convert_x(const float* __restrict__ x, unsigned short* __restrict__ xb, int n) {
    int i = blockIdx.x * 256 + threadIdx.x;
    if (i < n) xb[i] = f2bf(x[i]);
}

__global__ void build_wt(const float* __restrict__ Wq, const float* __restrict__ Wk,
                         const float* __restrict__ Wv, const float* __restrict__ Wg,
                         unsigned short* __restrict__ WT) {
    int i = blockIdx.x * 256 + threadIdx.x;   // over 3072*1024, WT[n][kk] = W(kk,n)
    if (i >= NPROJ * DM) return;
    int n = i >> 10, kk = i & 1023;
    float v;
    if (n < 512)       v = Wq[kk * 512 + n];
    else if (n < 1024) v = Wk[kk * 512 + (n - 512)];
    else if (n < 2048) v = Wv[kk * 1024 + (n - 1024)];
    else               v = Wg[kk * 1024 + (n - 2048)];
    WT[i] = f2bf(v);
}

__global__ void build_wot(const float* __restrict__ Wo, unsigned short* __restrict__ WoT) {
    int i = blockIdx.x * 256 + threadIdx.x;   // WoT[n][kk] = Wo[kk][n]
    if (i >= DM * DM) return;
    int n = i >> 10, kk = i & 1023;
    WoT[i] = f2bf(Wo[kk * 1024 + n]);
}

__global__ void beta_kernel(const float* __restrict__ x, const float* __restrict__ Wb,
                            float* __restrict__ beta) {
    int i = blockIdx.x * 256 + threadIdx.x;   // 0..32767 : (tok, h)
    int row = i >> 2, h = i & 3;
    const float* xr = x + (size_t)row * DM;
    float s = 0.f;
    #pragma unroll 8
    for (int kk = 0; kk < DM; kk++) s += xr[kk] * Wb[kk * 4 + h];
    beta[i] = 1.f / (1.f + __expf(-s));
}

// ---------------- bf16 MFMA GEMM: C[M][N] = A[M][K] * BT[N][K]^T ----------------
// 128x128 tile, BK=32, 4 waves (2x2), each wave 64x64 = 4x4 frags of 16x16x32.
template<int OUT_F32>
__global__ __launch_bounds__(256) void gemm_bt(
    const unsigned short* __restrict__ A, const unsigned short* __restrict__ BT,
    void* __restrict__ C, int M, int N, int K)
{
    __shared__ unsigned short As[128][40];   // pad to 40 bf16 (80B) per row
    __shared__ unsigned short Bs[128][40];
    int tid = threadIdx.x;
    int wave = tid >> 6, lane = tid & 63;
    int wr = (wave >> 1) * 64, wc = (wave & 1) * 64;
    int fr = lane & 15, fq = lane >> 4;      // frag row/col, k-group
    int m0 = blockIdx.x * 128, n0 = blockIdx.y * 128;

    f32x4 acc[4][4];
    #pragma unroll
    for (int i = 0; i < 4; i++)
        #pragma unroll
        for (int j = 0; j < 4; j++) acc[i][j] = (f32x4){0.f, 0.f, 0.f, 0.f};

    for (int k0 = 0; k0 < K; k0 += 32) {
        // stage A,B tiles: 512 16B-chunks each, 2+2 per thread
        #pragma unroll
        for (int r = 0; r < 2; r++) {
            int idx = tid + r * 256;              // 0..511
            int row = idx >> 2, c4 = idx & 3;     // 4 x 16B chunks per 64B row
            const unsigned short* ga = &A[(size_t)(m0 + row) * K + k0 + c4 * 8];
            *(short8v*)&As[row][c4 * 8] = *(const short8v*)ga;
            const unsigned short* gb = &BT[(size_t)(n0 + row) * K + k0 + c4 * 8];
            *(short8v*)&Bs[row][c4 * 8] = *(const short8v*)gb;
        }
        __syncthreads();
        short8v a[4], b[4];
        #pragma unroll
        for (int i = 0; i < 4; i++) {
            a[i] = *(const short8v*)&As[wr + i * 16 + fr][fq * 8];
            b[i] = *(const short8v*)&Bs[wc + i * 16 + fr][fq * 8];
        }
        #pragma unroll
        for (int i = 0; i < 4; i++)
            #pragma unroll
            for (int j = 0; j < 4; j++)
                acc[i][j] = __builtin_amdgcn_mfma_f32_16x16x32_bf16(a[i], b[j], acc[i][j], 0, 0, 0);
        __syncthreads();
    }
    // epilogue: D row = 4*fq + t, col = fr   (m89-verified)
    #pragma unroll
    for (int i = 0; i < 4; i++)
        #pragma unroll
        for (int j = 0; j < 4; j++)
            #pragma unroll
            for (int t = 0; t < 4; t++) {
                int row = m0 + wr + i * 16 + fq * 4 + t;
                int col = n0 + wc + j * 16 + fr;
                float val = acc[i][j][t];
                if (OUT_F32) ((float*)C)[(size_t)row * N + col] = val;
                else ((unsigned short*)C)[(size_t)row * N + col] = f2bf(val);
            }
}

// ---------------- normalize k rows (L2) and scale q ----------------
__global__ void norm_qk(unsigned short* __restrict__ QKVG) {
    int gid = blockIdx.x * 4 + (threadIdx.x >> 6);   // wave id = (tok,h), 32768 total
    int lane = threadIdx.x & 63;
    int tok = gid >> 2, h = gid & 3;
    size_t base = (size_t)tok * NPROJ;
    unsigned short* kp = QKVG + base + 512 + h * 128;
    float a = bf2f(kp[lane]), b = bf2f(kp[lane + 64]);
    float ss = a * a + b * b;
    #pragma unroll
    for (int off = 32; off; off >>= 1) ss += __shfl_xor(ss, off);
    float r = rsqrtf(ss + 1e-12f);
    kp[lane] = f2bf(a * r);
    kp[lane + 64] = f2bf(b * r);
    unsigned short* qp = QKVG + base + h * 128;
    const float SC = 0.08838834764831845f;           // 128^-0.5
    qp[lane] = f2bf(bf2f(qp[lane]) * SC);
    qp[lane + 64] = f2bf(bf2f(qp[lane + 64]) * SC);
}

// ---------------- per-chunk precompute: W = T bK, U = T bV, P = tril(QK^T) ----------------
// T = (I + strict_tril(diag(b) K K^T))^{-1}, solved by forward substitution.
__global__ __launch_bounds__(256) void chunk_pre(
    const unsigned short* __restrict__ QKVG, const float* __restrict__ beta,
    unsigned short* __restrict__ Wbuf, unsigned short* __restrict__ Ubuf,
    unsigned short* __restrict__ Pbuf)
{
    __shared__ float Kl[64][129];     // normalized k chunk (f32)
    __shared__ float Ml[64][65];      // M[t][s] = k_t . k_s (s<t)
    __shared__ float rows[64][385];   // [W|U] rows, 384 cols
    __shared__ float betas[64];
    int c = blockIdx.x, bh = blockIdx.y;
    int b = bh >> 2, h = bh & 3;
    int tid = threadIdx.x;
    int tok0 = b * SEQ + c * 64;

    for (int i = tid; i < 64 * 128; i += 256) {
        int t = i >> 7, d = i & 127;
        Kl[t][d] = bf2f(QKVG[(size_t)(tok0 + t) * NPROJ + 512 + h * 128 + d]);
    }
    if (tid < 64) betas[tid] = beta[(tok0 + tid) * 4 + h];
    __syncthreads();

    for (int i = tid; i < 64 * 64; i += 256) {
        int t = i >> 6, s = i & 63;
        if (s < t) {
            float acc = 0.f;
            #pragma unroll 8
            for (int d = 0; d < 128; d++) acc += Kl[t][d] * Kl[s][d];
            Ml[t][s] = acc;
        }
    }
    for (int i = tid; i < 64 * 384; i += 256) {
        int t = i / 384, cc = i - t * 384;
        float v = (cc < 128) ? Kl[t][cc]
                             : bf2f(QKVG[(size_t)(tok0 + t) * NPROJ + 1024 + h * 256 + (cc - 128)]);
        rows[t][cc] = betas[t] * v;
    }
    __syncthreads();
    // forward substitution: rows[t] -= beta_t * sum_{s<t} M[t][s]*rows[s]
    for (int t = 1; t < 64; t++) {
        float bt = betas[t];
        for (int cc = tid; cc < 384; cc += 256) {
            float acc = 0.f;
            for (int s = 0; s < t; s++) acc += Ml[t][s] * rows[s][cc];
            rows[t][cc] -= bt * acc;
        }
        __syncthreads();
    }
    size_t wbase = ((size_t)bh * NCHUNK + c) * (64 * 128);
    size_t ubase = ((size_t)bh * NCHUNK + c) * (64 * 256);
    size_t pbase = ((size_t)bh * NCHUNK + c) * (64 * 64);
    for (int i = tid; i < 64 * 128; i += 256) {
        int t = i >> 7, d = i & 127;
        Wbuf[wbase + i] = f2bf(rows[t][d]);
    }
    for (int i = tid; i < 64 * 256; i += 256) {
        int t = i >> 8, j = i & 255;
        Ubuf[ubase + i] = f2bf(rows[t][128 + j]);
    }
    for (int i = tid; i < 64 * 64; i += 256) {
        int t = i >> 6, s = i & 63;
        float val = 0.f;
        if (s <= t) {
            float acc = 0.f;
            #pragma unroll 8
            for (int d = 0; d < 128; d++)
                acc += bf2f(QKVG[(size_t)(tok0 + t) * NPROJ + h * 128 + d]) * Kl[s][d];
            val = acc;
        }
        Pbuf[pbase + i] = f2bf(val);
    }
}

// ---------------- sequential chunk scan per (bh, dv-slice of 16) ----------------
// Delta = U - W*S ; O = Q*S + P*Delta ; S += K^T Delta
__global__ __launch_bounds__(256) void scan(
    const unsigned short* __restrict__ QKVG, const unsigned short* __restrict__ Wbuf,
    const unsigned short* __restrict__ Ubuf, const unsigned short* __restrict__ Pbuf,
    unsigned short* __restrict__ Ob)
{
    __shared__ float S[128][17];   // state slice S[d][jj]
    __shared__ float Dl[64][17];   // delta slice
    int sl = blockIdx.x;           // 0..15
    int bh = blockIdx.y;
    int b = bh >> 2, h = bh & 3;
    int j0 = sl * 16;
    int tid = threadIdx.x;
    int jj = tid & 15, tg = tid >> 4;   // 16 col lanes x 16 groups

    for (int i = tid; i < 128 * 16; i += 256) S[i >> 4][i & 15] = 0.f;
    __syncthreads();

    for (int c = 0; c < NCHUNK; c++) {
        size_t wbase = ((size_t)bh * NCHUNK + c) * (64 * 128);
        size_t ubase = ((size_t)bh * NCHUNK + c) * (64 * 256);
        size_t pbase = ((size_t)bh * NCHUNK + c) * (64 * 64);
        int tok0 = b * SEQ + c * 64;
        // phase 1: Dl[t][jj] = U[t][j0+jj] - sum_d W[t][d]*S[d][jj]
        for (int t = tg; t < 64; t += 16) {
            const unsigned short* wrow = Wbuf + wbase + t * 128;
            float acc = 0.f;
            #pragma unroll 8
            for (int d = 0; d < 128; d++) acc += bf2f(wrow[d]) * S[d][jj];
            Dl[t][jj] = bf2f(Ubuf[ubase + t * 256 + j0 + jj]) - acc;
        }
        __syncthreads();
        // phase 2: O[t][j] = sum_d Q[t][d]*S[d][jj] + sum_s P[t][s]*Dl[s][jj]
        for (int t = tg; t < 64; t += 16) {
            const unsigned short* qrow = QKVG + (size_t)(tok0 + t) * NPROJ + h * 128;
            const unsigned short* prow = Pbuf + pbase + t * 64;
            float acc = 0.f;
            #pragma unroll 8
            for (int d = 0; d < 128; d++) acc += bf2f(qrow[d]) * S[d][jj];
            #pragma unroll 8
            for (int s = 0; s < 64; s++) acc += bf2f(prow[s]) * Dl[s][jj];
            Ob[(size_t)(tok0 + t) * 1024 + h * 256 + j0 + jj] = f2bf(acc);
        }
        __syncthreads();
        // phase 3: S[d][jj] += sum_t K[t][d]*Dl[t][jj]
        for (int d = tg; d < 128; d += 16) {
            float acc = 0.f;
            #pragma unroll 8
            for (int t = 0; t < 64; t++)
                acc += bf2f(QKVG[(size_t)(tok0 + t) * NPROJ + 512 + h * 128 + d]) * Dl[t][jj];
            S[d][jj] += acc;
        }
        __syncthreads();
    }
}

// ---------------- RMSNorm + swish gate ----------------
__global__ void gate_norm(const unsigned short* __restrict__ Ob,
                          const unsigned short* __restrict__ QKVG,
                          const float* __restrict__ norm_w,
                          unsigned short* __restrict__ o2)
{
    __shared__ float red[4];
    int tok = blockIdx.x >> 2, h = blockIdx.x & 3;
    int j = threadIdx.x;
    float o = bf2f(Ob[(size_t)tok * 1024 + h * 256 + j]);
    float ss = o * o;
    #pragma unroll
    for (int off = 32; off; off >>= 1) ss += __shfl_xor(ss, off);
    if ((threadIdx.x & 63) == 0) red[threadIdx.x >> 6] = ss;
    __syncthreads();
    float tot = red[0] + red[1] + red[2] + red[3];
    float r = rsqrtf(tot * (1.0f / 256.0f) + 1e-5f);
    float g = bf2f(QKVG[(size_t)tok * NPROJ + 2048 + h * 256 + j]);
    float sw = g / (1.f + __expf(-g));
    o2[(size_t)tok * 1024 + h * 256 + j] = f2bf(o * r * norm_w[j] * sw);
}

// ---------------- launch ----------------
extern "C" void kernel_launch(void* const* d_in, const int* in_sizes, int n_in,
                              void* d_out, int out_size, void* d_ws, size_t ws_size,
                              hipStream_t stream) {
    const float* x      = (const float*)d_in[0];
    const float* Wq     = (const float*)d_in[1];
    const float* Wk     = (const float*)d_in[2];
    const float* Wv     = (const float*)d_in[3];
    const float* Wb     = (const float*)d_in[4];
    const float* Wg     = (const float*)d_in[5];
    const float* Wo     = (const float*)d_in[6];
    const float* norm_w = (const float*)d_in[7];
    float* out = (float*)d_out;

    char* ws = (char*)d_ws;
    unsigned short* xb   = (unsigned short*)(ws + 0);          // 16,777,216
    unsigned short* WT   = (unsigned short*)(ws + 16777216);   //  6,291,456
    unsigned short* WoT  = (unsigned short*)(ws + 23068672);   //  2,097,152
    unsigned short* QKVG = (unsigned short*)(ws + 25165824);   // 50,331,648
    float*          beta = (float*)        (ws + 75497472);    //    131,072
    unsigned short* Wbuf = (unsigned short*)(ws + 75628544);   //  8,388,608
    unsigned short* Ubuf = (unsigned short*)(ws + 84017152);   // 16,777,216
    unsigned short* Pbuf = (unsigned short*)(ws + 100794368);  //  4,194,304
    unsigned short* Ob   = (unsigned short*)(ws + 104988672);  // 16,777,216
    unsigned short* o2   = (unsigned short*)(ws + 121765888);  // 16,777,216  (total ~138.5MB)

    convert_x<<<(NTOK * DM + 255) / 256, 256, 0, stream>>>(x, xb, NTOK * DM);
    build_wt<<<(NPROJ * DM + 255) / 256, 256, 0, stream>>>(Wq, Wk, Wv, Wg, WT);
    build_wot<<<(DM * DM + 255) / 256, 256, 0, stream>>>(Wo, WoT);
    beta_kernel<<<(NTOK * 4) / 256, 256, 0, stream>>>(x, Wb, beta);
    gemm_bt<0><<<dim3(64, 24), 256, 0, stream>>>(xb, WT, (void*)QKVG, NTOK, NPROJ, DM);
    norm_qk<<<NTOK * 4 / 4, 256, 0, stream>>>(QKVG);
    chunk_pre<<<dim3(NCHUNK, 8), 256, 0, stream>>>(QKVG, beta, Wbuf, Ubuf, Pbuf);
    scan<<<dim3(16, 8), 256, 0, stream>>>(QKVG, Wbuf, Ubuf, Pbuf, Ob);
    gate_norm<<<NTOK * 4, 256, 0, stream>>>(Ob, QKVG, norm_w, o2);
    gemm_bt<1><<<dim3(64, 8), 256, 0, stream>>>(o2, WoT, (void*)out, NTOK, DM, DM);
}

// Round 2
// 877.802 us; speedup vs baseline: 3.5638x; 3.5638x over previous
//
#include <hip/hip_runtime.h>
#include <hip/hip_bf16.h>
#include <stdint.h>
#include <stddef.h>

typedef __attribute__((ext_vector_type(8))) short short8v;  // 8 bf16 = 4 VGPR
typedef __attribute__((ext_vector_type(4))) float f32x4;

__device__ __forceinline__ float bf2f(unsigned short u) {
    return __uint_as_float(((unsigned int)u) << 16);
}
__device__ __forceinline__ unsigned short f2bf(float f) {
    unsigned int x = __float_as_uint(f);
    x += 0x7fffu + ((x >> 16) & 1u);   // RNE
    return (unsigned short)(x >> 16);
}

#define NTOK 8192      // b*n
#define DM   1024
#define NPROJ 3072     // q512 | k512 | v1024 | g1024
#define SEQ  4096
#define NCHUNK 64      // chunks per sequence (4096/64)

// swizzled LDS element offsets (2B elems). 256B rows (16 units of 16B):
__device__ __forceinline__ int sw16(int row, int k) {
    int u = k >> 3;
    int us = (u & 8) | ((u ^ row) & 7);
    return row * 128 + us * 8 + (k & 7);
}
// 128B rows (8 units):
__device__ __forceinline__ int sw8(int row, int k) {
    int u = k >> 3;
    int us = (u ^ row) & 7;
    return row * 64 + us * 8 + (k & 7);
}

// ---------------- elementwise / conversion ----------------
__global__ void convert_x(const float* __restrict__ x, unsigned short* __restrict__ xb, int n) {
    int i = blockIdx.x * 256 + threadIdx.x;
    if (i < n) xb[i] = f2bf(x[i]);
}

__global__ void build_wt(const float* __restrict__ Wq, const float* __restrict__ Wk,
                         const float* __restrict__ Wv, const float* __restrict__ Wg,
                         unsigned short* __restrict__ WT) {
    int i = blockIdx.x * 256 + threadIdx.x;   // WT[n][kk] = W(kk,n)
    if (i >= NPROJ * DM) return;
    int n = i >> 10, kk = i & 1023;
    float v;
    if (n < 512)       v = Wq[kk * 512 + n];
    else if (n < 1024) v = Wk[kk * 512 + (n - 512)];
    else if (n < 2048) v = Wv[kk * 1024 + (n - 1024)];
    else               v = Wg[kk * 1024 + (n - 2048)];
    WT[i] = f2bf(v);
}

__global__ void build_wot(const float* __restrict__ Wo, unsigned short* __restrict__ WoT) {
    int i = blockIdx.x * 256 + threadIdx.x;   // WoT[n][kk] = Wo[kk][n]
    if (i >= DM * DM) return;
    int n = i >> 10, kk = i & 1023;
    WoT[i] = f2bf(Wo[kk * 1024 + n]);
}

// beta: block handles 16 tokens; 16 seg-threads per token, float4 loads.
__global__ __launch_bounds__(256) void beta_kernel(const float* __restrict__ x,
                                                   const float* __restrict__ Wb,
                                                   float* __restrict__ beta) {
    __shared__ float part[16][16][4];
    int tl = threadIdx.x >> 4, sg = threadIdx.x & 15;
    int tok = blockIdx.x * 16 + tl;
    const float4* xr = (const float4*)(x + (size_t)tok * DM);
    const float4* wb = (const float4*)Wb;
    float s0 = 0.f, s1 = 0.f, s2 = 0.f, s3 = 0.f;
    #pragma unroll
    for (int it = 0; it < 16; it++) {
        int f = it * 16 + sg;
        float4 xv = xr[f];
        float4 w0 = wb[4 * f + 0], w1 = wb[4 * f + 1], w2 = wb[4 * f + 2], w3 = wb[4 * f + 3];
        s0 += xv.x * w0.x + xv.y * w1.x + xv.z * w2.x + xv.w * w3.x;
        s1 += xv.x * w0.y + xv.y * w1.y + xv.z * w2.y + xv.w * w3.y;
        s2 += xv.x * w0.z + xv.y * w1.z + xv.z * w2.z + xv.w * w3.z;
        s3 += xv.x * w0.w + xv.y * w1.w + xv.z * w2.w + xv.w * w3.w;
    }
    part[tl][sg][0] = s0; part[tl][sg][1] = s1; part[tl][sg][2] = s2; part[tl][sg][3] = s3;
    __syncthreads();
    if (threadIdx.x < 64) {
        int tl2 = threadIdx.x >> 2, h = threadIdx.x & 3;
        float s = 0.f;
        #pragma unroll
        for (int g = 0; g < 16; g++) s += part[tl2][g][h];
        beta[(size_t)(blockIdx.x * 16 + tl2) * 4 + h] = 1.f / (1.f + __expf(-s));
    }
}

// ---------------- bf16 MFMA GEMM: C[M][N] = A[M][K] * BT[N][K]^T ----------------
template<int OUT_F32>
__global__ __launch_bounds__(256) void gemm_bt(
    const unsigned short* __restrict__ A, const unsigned short* __restrict__ BT,
    void* __restrict__ C, int M, int N, int K)
{
    __shared__ unsigned short As[128][40];
    __shared__ unsigned short Bs[128][40];
    int tid = threadIdx.x;
    int wave = tid >> 6, lane = tid & 63;
    int wr = (wave >> 1) * 64, wc = (wave & 1) * 64;
    int fr = lane & 15, fq = lane >> 4;
    int m0 = blockIdx.x * 128, n0 = blockIdx.y * 128;

    f32x4 acc[4][4];
    #pragma unroll
    for (int i = 0; i < 4; i++)
        #pragma unroll
        for (int j = 0; j < 4; j++) acc[i][j] = (f32x4){0.f, 0.f, 0.f, 0.f};

    for (int k0 = 0; k0 < K; k0 += 32) {
        #pragma unroll
        for (int r = 0; r < 2; r++) {
            int idx = tid + r * 256;
            int row = idx >> 2, c4 = idx & 3;
            const unsigned short* ga = &A[(size_t)(m0 + row) * K + k0 + c4 * 8];
            *(short8v*)&As[row][c4 * 8] = *(const short8v*)ga;
            const unsigned short* gb = &BT[(size_t)(n0 + row) * K + k0 + c4 * 8];
            *(short8v*)&Bs[row][c4 * 8] = *(const short8v*)gb;
        }
        __syncthreads();
        short8v a[4], b[4];
        #pragma unroll
        for (int i = 0; i < 4; i++) {
            a[i] = *(const short8v*)&As[wr + i * 16 + fr][fq * 8];
            b[i] = *(const short8v*)&Bs[wc + i * 16 + fr][fq * 8];
        }
        #pragma unroll
        for (int i = 0; i < 4; i++)
            #pragma unroll
            for (int j = 0; j < 4; j++)
                acc[i][j] = __builtin_amdgcn_mfma_f32_16x16x32_bf16(a[i], b[j], acc[i][j], 0, 0, 0);
        __syncthreads();
    }
    #pragma unroll
    for (int i = 0; i < 4; i++)
        #pragma unroll
        for (int j = 0; j < 4; j++)
            #pragma unroll
            for (int t = 0; t < 4; t++) {
                int row = m0 + wr + i * 16 + fq * 4 + t;
                int col = n0 + wc + j * 16 + fr;
                float val = acc[i][j][t];
                if (OUT_F32) ((float*)C)[(size_t)row * N + col] = val;
                else ((unsigned short*)C)[(size_t)row * N + col] = f2bf(val);
            }
}

// ---------------- normalize k rows (L2) and scale q ----------------
__global__ void norm_qk(unsigned short* __restrict__ QKVG) {
    int gid = blockIdx.x * 4 + (threadIdx.x >> 6);
    int lane = threadIdx.x & 63;
    int tok = gid >> 2, h = gid & 3;
    size_t base = (size_t)tok * NPROJ;
    unsigned short* kp = QKVG + base + 512 + h * 128;
    float a = bf2f(kp[lane]), b = bf2f(kp[lane + 64]);
    float ss = a * a + b * b;
    #pragma unroll
    for (int off = 32; off; off >>= 1) ss += __shfl_xor(ss, off);
    float r = rsqrtf(ss + 1e-12f);
    kp[lane] = f2bf(a * r);
    kp[lane + 64] = f2bf(b * r);
    unsigned short* qp = QKVG + base + h * 128;
    const float SC = 0.08838834764831845f;
    qp[lane] = f2bf(bf2f(qp[lane]) * SC);
    qp[lane + 64] = f2bf(bf2f(qp[lane + 64]) * SC);
}

// ---------------- per-chunk precompute: W = T bK, U = T bV, P = tril(QK^T), KT ----------------
__global__ __launch_bounds__(256) void chunk_pre(
    const unsigned short* __restrict__ QKVG, const float* __restrict__ beta,
    unsigned short* __restrict__ Wbuf, unsigned short* __restrict__ Ubuf,
    unsigned short* __restrict__ Pbuf, unsigned short* __restrict__ KTbuf)
{
    __shared__ float Kl[64][129];
    __shared__ float Ml[64][65];
    __shared__ float rows[64][385];
    __shared__ float betas[64];
    int c = blockIdx.x, bh = blockIdx.y;
    int b = bh >> 2, h = bh & 3;
    int tid = threadIdx.x;
    int tok0 = b * SEQ + c * 64;

    for (int i = tid; i < 64 * 128; i += 256) {
        int t = i >> 7, d = i & 127;
        Kl[t][d] = bf2f(QKVG[(size_t)(tok0 + t) * NPROJ + 512 + h * 128 + d]);
    }
    if (tid < 64) betas[tid] = beta[(tok0 + tid) * 4 + h];
    __syncthreads();

    for (int i = tid; i < 64 * 64; i += 256) {
        int t = i >> 6, s = i & 63;
        if (s < t) {
            float acc = 0.f;
            #pragma unroll 8
            for (int d = 0; d < 128; d++) acc += Kl[t][d] * Kl[s][d];
            Ml[t][s] = acc;
        }
    }
    for (int i = tid; i < 64 * 384; i += 256) {
        int t = i / 384, cc = i - t * 384;
        float v = (cc < 128) ? Kl[t][cc]
                             : bf2f(QKVG[(size_t)(tok0 + t) * NPROJ + 1024 + h * 256 + (cc - 128)]);
        rows[t][cc] = betas[t] * v;
    }
    __syncthreads();
    for (int t = 1; t < 64; t++) {
        float bt = betas[t];
        for (int cc = tid; cc < 384; cc += 256) {
            float acc = 0.f;
            for (int s = 0; s < t; s++) acc += Ml[t][s] * rows[s][cc];
            rows[t][cc] -= bt * acc;
        }
        __syncthreads();
    }
    size_t wbase = ((size_t)bh * NCHUNK + c) * (64 * 128);
    size_t ubase = ((size_t)bh * NCHUNK + c) * (64 * 256);
    size_t pbase = ((size_t)bh * NCHUNK + c) * (64 * 64);
    size_t ktb  = ((size_t)bh * NCHUNK + c) * (128 * 64);
    for (int i = tid; i < 64 * 128; i += 256) {
        int t = i >> 7, d = i & 127;
        Wbuf[wbase + i] = f2bf(rows[t][d]);
    }
    for (int i = tid; i < 64 * 256; i += 256) {
        int t = i >> 8, j = i & 255;
        Ubuf[ubase + i] = f2bf(rows[t][128 + j]);
    }
    for (int i = tid; i < 128 * 64; i += 256) {
        int d = i >> 6, t = i & 63;
        KTbuf[ktb + i] = f2bf(Kl[t][d]);
    }
    for (int i = tid; i < 64 * 64; i += 256) {
        int t = i >> 6, s = i & 63;
        float val = 0.f;
        if (s <= t) {
            float acc = 0.f;
            #pragma unroll 8
            for (int d = 0; d < 128; d++)
                acc += bf2f(QKVG[(size_t)(tok0 + t) * NPROJ + h * 128 + d]) * Kl[s][d];
            val = acc;
        }
        Pbuf[pbase + i] = f2bf(val);
    }
}

// ---------------- MFMA chunk scan ----------------
// grid (4 dv-slices, 8 bh), 256 threads. State S[128][64] f32 in MFMA accumulators.
// LDS (elems of 2B): double buf {W 8192, Q 8192, KT 8192, P 4096, U 4224} = 32896 x2,
// then ST 8192, DT 4096. Total 78080 elems = 156160 B.
#define SBUF   32896
#define SW_OFF 0
#define SQ_OFF 8192
#define SKT_OFF 16384
#define SP_OFF 24576
#define SU_OFF 28672
#define SST_OFF (2 * SBUF)
#define SDT_OFF (2 * SBUF + 8192)

__global__ __launch_bounds__(256, 1) void scan_mfma(
    const unsigned short* __restrict__ QKVG, const unsigned short* __restrict__ Wbuf,
    const unsigned short* __restrict__ Ubuf, const unsigned short* __restrict__ Pbuf,
    const unsigned short* __restrict__ KTbuf, unsigned short* __restrict__ Ob)
{
    extern __shared__ unsigned short lds[];
    int tid = threadIdx.x;
    int wv = tid >> 6, ln = tid & 63;
    int fr = ln & 15, fq = ln >> 4;
    int j0 = blockIdx.x * 64;
    int bh = blockIdx.y;
    int b = bh >> 2, h = bh & 3;

    unsigned short* ST = lds + SST_OFF;
    unsigned short* DT = lds + SDT_OFF;

    f32x4 sacc[2][4];
    #pragma unroll
    for (int i = 0; i < 2; i++)
        #pragma unroll
        for (int j = 0; j < 4; j++) sacc[i][j] = (f32x4){0.f, 0.f, 0.f, 0.f};

    short8v rg[16];
    auto issue = [&](int c1) {
        size_t cb = (size_t)bh * NCHUNK + c1;
        const unsigned short* Wc = Wbuf + cb * (64 * 128);
        const unsigned short* Uc = Ubuf + cb * (64 * 256);
        const unsigned short* Pc = Pbuf + cb * (64 * 64);
        const unsigned short* Kc = KTbuf + cb * (128 * 64);
        int tok0 = b * SEQ + c1 * 64;
        #pragma unroll
        for (int i = 0; i < 4; i++) {
            int p = tid + 256 * i;
            int t = p >> 4, up = p & 15;
            int u = (up & 8) | ((up ^ t) & 7);
            rg[i] = *(const short8v*)(Wc + t * 128 + u * 8);
            rg[4 + i] = *(const short8v*)(QKVG + (size_t)(tok0 + t) * NPROJ + h * 128 + u * 8);
            int d = p >> 3;
            int u8 = (p ^ d) & 7;
            rg[8 + i] = *(const short8v*)(Kc + d * 64 + u8 * 8);
        }
        #pragma unroll
        for (int i = 0; i < 2; i++) {
            int p = tid + 256 * i;
            int t = p >> 3;
            int u8 = (p ^ t) & 7;
            rg[12 + i] = *(const short8v*)(Pc + t * 64 + u8 * 8);
            rg[14 + i] = *(const short8v*)(Uc + t * 256 + j0 + (p & 7) * 8);
        }
    };
    auto commit = [&](unsigned short* bb) {
        #pragma unroll
        for (int i = 0; i < 4; i++) {
            int p = tid + 256 * i;
            *(short8v*)(bb + SW_OFF + p * 8) = rg[i];
            *(short8v*)(bb + SQ_OFF + p * 8) = rg[4 + i];
            *(short8v*)(bb + SKT_OFF + p * 8) = rg[8 + i];
        }
        #pragma unroll
        for (int i = 0; i < 2; i++) {
            int p = tid + 256 * i;
            *(short8v*)(bb + SP_OFF + p * 8) = rg[12 + i];
            *(short8v*)(bb + SU_OFF + (p >> 3) * 66 + (p & 7) * 8) = rg[14 + i];
        }
    };

    issue(0);
    commit(lds);
    __syncthreads();

    for (int c = 0; c < NCHUNK; c++) {
        unsigned short* ba = (c & 1) ? (lds + SBUF) : lds;
        unsigned short* bb = (c & 1) ? lds : (lds + SBUF);
        if (c < NCHUNK - 1) issue(c + 1);

        // dump state S -> ST[j][d] bf16 (swizzled)
        #pragma unroll
        for (int dtt = 0; dtt < 2; dtt++)
            #pragma unroll
            for (int jt = 0; jt < 4; jt++) {
                int d0 = 32 * wv + 16 * dtt + 4 * fq;
                int j = 16 * jt + fr;
                f32x4 v = sacc[dtt][jt];
                unsigned int lo = f2bf(v[0]) | ((unsigned)f2bf(v[1]) << 16);
                unsigned int hi = f2bf(v[2]) | ((unsigned)f2bf(v[3]) << 16);
                *(uint2*)&ST[sw16(j, d0)] = make_uint2(lo, hi);
            }
        __syncthreads();

        // merged: dacc = W*S, oacc = Q*S  (wave owns t-band 16*wv)
        f32x4 dacc[4], oacc[4];
        #pragma unroll
        for (int jt = 0; jt < 4; jt++) {
            dacc[jt] = (f32x4){0.f, 0.f, 0.f, 0.f};
            oacc[jt] = (f32x4){0.f, 0.f, 0.f, 0.f};
        }
        #pragma unroll
        for (int ks = 0; ks < 4; ks++) {
            short8v aw = *(const short8v*)(ba + SW_OFF + sw16(16 * wv + fr, 32 * ks + 8 * fq));
            short8v aq = *(const short8v*)(ba + SQ_OFF + sw16(16 * wv + fr, 32 * ks + 8 * fq));
            #pragma unroll
            for (int jt = 0; jt < 4; jt++) {
                short8v bs = *(const short8v*)(ST + sw16(16 * jt + fr, 32 * ks + 8 * fq));
                dacc[jt] = __builtin_amdgcn_mfma_f32_16x16x32_bf16(aw, bs, dacc[jt], 0, 0, 0);
                oacc[jt] = __builtin_amdgcn_mfma_f32_16x16x32_bf16(aq, bs, oacc[jt], 0, 0, 0);
            }
        }
        // Delta = U - dacc -> DT[j][t] bf16 (swizzled)
        #pragma unroll
        for (int jt = 0; jt < 4; jt++) {
            int j = 16 * jt + fr;
            int t0 = 16 * wv + 4 * fq;
            float v0 = bf2f(ba[SU_OFF + (t0 + 0) * 66 + j]) - dacc[jt][0];
            float v1 = bf2f(ba[SU_OFF + (t0 + 1) * 66 + j]) - dacc[jt][1];
            float v2 = bf2f(ba[SU_OFF + (t0 + 2) * 66 + j]) - dacc[jt][2];
            float v3 = bf2f(ba[SU_OFF + (t0 + 3) * 66 + j]) - dacc[jt][3];
            unsigned int lo = f2bf(v0) | ((unsigned)f2bf(v1) << 16);
            unsigned int hi = f2bf(v2) | ((unsigned)f2bf(v3) << 16);
            *(uint2*)&DT[sw8(j, t0)] = make_uint2(lo, hi);
        }
        __syncthreads();

        // oacc += P * Delta
        #pragma unroll
        for (int ks = 0; ks < 2; ks++) {
            short8v ap = *(const short8v*)(ba + SP_OFF + sw8(16 * wv + fr, 32 * ks + 8 * fq));
            #pragma unroll
            for (int jt = 0; jt < 4; jt++) {
                short8v bd = *(const short8v*)(DT + sw8(16 * jt + fr, 32 * ks + 8 * fq));
                oacc[jt] = __builtin_amdgcn_mfma_f32_16x16x32_bf16(ap, bd, oacc[jt], 0, 0, 0);
            }
        }
        // S += K^T * Delta  (wave owns d-band 32*wv)
        #pragma unroll
        for (int ks = 0; ks < 2; ks++) {
            short8v ak0 = *(const short8v*)(ba + SKT_OFF + sw8(32 * wv + fr, 32 * ks + 8 * fq));
            short8v ak1 = *(const short8v*)(ba + SKT_OFF + sw8(32 * wv + 16 + fr, 32 * ks + 8 * fq));
            #pragma unroll
            for (int jt = 0; jt < 4; jt++) {
                short8v bd = *(const short8v*)(DT + sw8(16 * jt + fr, 32 * ks + 8 * fq));
                sacc[0][jt] = __builtin_amdgcn_mfma_f32_16x16x32_bf16(ak0, bd, sacc[0][jt], 0, 0, 0);
                sacc[1][jt] = __builtin_amdgcn_mfma_f32_16x16x32_bf16(ak1, bd, sacc[1][jt], 0, 0, 0);
            }
        }
        // O store
        int tok0 = b * SEQ + c * 64;
        #pragma unroll
        for (int jt = 0; jt < 4; jt++)
            #pragma unroll
            for (int r = 0; r < 4; r++) {
                int t = 16 * wv + 4 * fq + r;
                Ob[(size_t)(tok0 + t) * 1024 + h * 256 + j0 + 16 * jt + fr] = f2bf(oacc[jt][r]);
            }
        if (c < NCHUNK - 1) commit(bb);
        __syncthreads();
    }
}

// ---------------- RMSNorm + swish gate ----------------
__global__ void gate_norm(const unsigned short* __restrict__ Ob,
                          const unsigned short* __restrict__ QKVG,
                          const float* __restrict__ norm_w,
                          unsigned short* __restrict__ o2)
{
    __shared__ float red[4];
    int tok = blockIdx.x >> 2, h = blockIdx.x & 3;
    int j = threadIdx.x;
    float o = bf2f(Ob[(size_t)tok * 1024 + h * 256 + j]);
    float ss = o * o;
    #pragma unroll
    for (int off = 32; off; off >>= 1) ss += __shfl_xor(ss, off);
    if ((threadIdx.x & 63) == 0) red[threadIdx.x >> 6] = ss;
    __syncthreads();
    float tot = red[0] + red[1] + red[2] + red[3];
    float r = rsqrtf(tot * (1.0f / 256.0f) + 1e-5f);
    float g = bf2f(QKVG[(size_t)tok * NPROJ + 2048 + h * 256 + j]);
    float sw = g / (1.f + __expf(-g));
    o2[(size_t)tok * 1024 + h * 256 + j] = f2bf(o * r * norm_w[j] * sw);
}

// ---------------- launch ----------------
extern "C" void kernel_launch(void* const* d_in, const int* in_sizes, int n_in,
                              void* d_out, int out_size, void* d_ws, size_t ws_size,
                              hipStream_t stream) {
    const float* x      = (const float*)d_in[0];
    const float* Wq     = (const float*)d_in[1];
    const float* Wk     = (const float*)d_in[2];
    const float* Wv     = (const float*)d_in[3];
    const float* Wb     = (const float*)d_in[4];
    const float* Wg     = (const float*)d_in[5];
    const float* Wo     = (const float*)d_in[6];
    const float* norm_w = (const float*)d_in[7];
    float* out = (float*)d_out;

    char* ws = (char*)d_ws;
    unsigned short* xb   = (unsigned short*)(ws + 0);          // 16,777,216
    unsigned short* KTbuf= (unsigned short*)(ws + 0);          // aliases xb (dead after gemm<0>)
    unsigned short* WT   = (unsigned short*)(ws + 16777216);   //  6,291,456
    unsigned short* WoT  = (unsigned short*)(ws + 23068672);   //  2,097,152
    unsigned short* QKVG = (unsigned short*)(ws + 25165824);   // 50,331,648
    float*          beta = (float*)        (ws + 75497472);    //    131,072
    unsigned short* Wbuf = (unsigned short*)(ws + 75628544);   //  8,388,608
    unsigned short* Ubuf = (unsigned short*)(ws + 84017152);   // 16,777,216
    unsigned short* Pbuf = (unsigned short*)(ws + 100794368);  //  4,194,304
    unsigned short* Ob   = (unsigned short*)(ws + 104988672);  // 16,777,216
    unsigned short* o2   = (unsigned short*)(ws + 121765888);  // 16,777,216

    (void)hipFuncSetAttribute((const void*)scan_mfma,
                              hipFuncAttributeMaxDynamicSharedMemorySize, 156160);

    convert_x<<<(NTOK * DM + 255) / 256, 256, 0, stream>>>(x, xb, NTOK * DM);
    build_wt<<<(NPROJ * DM + 255) / 256, 256, 0, stream>>>(Wq, Wk, Wv, Wg, WT);
    build_wot<<<(DM * DM + 255) / 256, 256, 0, stream>>>(Wo, WoT);
    beta_kernel<<<NTOK / 16, 256, 0, stream>>>(x, Wb, beta);
    gemm_bt<0><<<dim3(64, 24), 256, 0, stream>>>(xb, WT, (void*)QKVG, NTOK, NPROJ, DM);
    norm_qk<<<NTOK * 4 / 4, 256, 0, stream>>>(QKVG);
    chunk_pre<<<dim3(NCHUNK, 8), 256, 0, stream>>>(QKVG, beta, Wbuf, Ubuf, Pbuf, KTbuf);
    scan_mfma<<<dim3(4, 8), 256, 156160, stream>>>(QKVG, Wbuf, Ubuf, Pbuf, KTbuf, Ob);
    gate_norm<<<NTOK * 4, 256, 0, stream>>>(Ob, QKVG, norm_w, o2);
    gemm_bt<1><<<dim3(64, 8), 256, 0, stream>>>(o2, WoT, (void*)out, NTOK, DM, DM);
}

// Round 3
// 450.498 us; speedup vs baseline: 6.9442x; 1.9485x over previous
//
#include <hip/hip_runtime.h>
#include <hip/hip_bf16.h>
#include <stdint.h>
#include <stddef.h>

typedef __attribute__((ext_vector_type(8))) short short8v;  // 8 bf16 = 4 VGPR
typedef __attribute__((ext_vector_type(4))) float f32x4;

__device__ __forceinline__ float bf2f(unsigned short u) {
    return __uint_as_float(((unsigned int)u) << 16);
}
__device__ __forceinline__ unsigned short f2bf(float f) {
    unsigned int x = __float_as_uint(f);
    x += 0x7fffu + ((x >> 16) & 1u);   // RNE
    return (unsigned short)(x >> 16);
}

#define NTOK 8192      // b*n
#define DM   1024
#define NPROJ 3072     // q512 | k512 | v1024 | g1024
#define SEQ  4096
#define NCHUNK 64      // chunks per sequence (4096/64)
#define SCQ 0.08838834764831845f   // 128^-0.5

// swizzled LDS element offsets (2B elems). 256B rows (16 units of 16B):
__device__ __forceinline__ int sw16(int row, int k) {
    int u = k >> 3;
    int us = (u & 8) | ((u ^ row) & 7);
    return row * 128 + us * 8 + (k & 7);
}
// 128B rows (8 units):
__device__ __forceinline__ int sw8(int row, int k) {
    int u = k >> 3;
    int us = (u ^ row) & 7;
    return row * 64 + us * 8 + (k & 7);
}

// ---------------- elementwise / conversion ----------------
__global__ void convert_x(const float* __restrict__ x, unsigned short* __restrict__ xb, int n) {
    int i = blockIdx.x * 256 + threadIdx.x;
    if (i < n) xb[i] = f2bf(x[i]);
}

__global__ void build_wt(const float* __restrict__ Wq, const float* __restrict__ Wk,
                         const float* __restrict__ Wv, const float* __restrict__ Wg,
                         unsigned short* __restrict__ WT) {
    int i = blockIdx.x * 256 + threadIdx.x;   // WT[n][kk] = W(kk,n)
    if (i >= NPROJ * DM) return;
    int n = i >> 10, kk = i & 1023;
    float v;
    if (n < 512)       v = Wq[kk * 512 + n];
    else if (n < 1024) v = Wk[kk * 512 + (n - 512)];
    else if (n < 2048) v = Wv[kk * 1024 + (n - 1024)];
    else               v = Wg[kk * 1024 + (n - 2048)];
    WT[i] = f2bf(v);
}

__global__ void build_wot(const float* __restrict__ Wo, unsigned short* __restrict__ WoT) {
    int i = blockIdx.x * 256 + threadIdx.x;   // WoT[n][kk] = Wo[kk][n]
    if (i >= DM * DM) return;
    int n = i >> 10, kk = i & 1023;
    WoT[i] = f2bf(Wo[kk * 1024 + n]);
}

// beta: block handles 16 tokens; 16 seg-threads per token, float4 loads.
__global__ __launch_bounds__(256) void beta_kernel(const float* __restrict__ x,
                                                   const float* __restrict__ Wb,
                                                   float* __restrict__ beta) {
    __shared__ float part[16][16][4];
    int tl = threadIdx.x >> 4, sg = threadIdx.x & 15;
    int tok = blockIdx.x * 16 + tl;
    const float4* xr = (const float4*)(x + (size_t)tok * DM);
    const float4* wb = (const float4*)Wb;
    float s0 = 0.f, s1 = 0.f, s2 = 0.f, s3 = 0.f;
    #pragma unroll
    for (int it = 0; it < 16; it++) {
        int f = it * 16 + sg;
        float4 xv = xr[f];
        float4 w0 = wb[4 * f + 0], w1 = wb[4 * f + 1], w2 = wb[4 * f + 2], w3 = wb[4 * f + 3];
        s0 += xv.x * w0.x + xv.y * w1.x + xv.z * w2.x + xv.w * w3.x;
        s1 += xv.x * w0.y + xv.y * w1.y + xv.z * w2.y + xv.w * w3.y;
        s2 += xv.x * w0.z + xv.y * w1.z + xv.z * w2.z + xv.w * w3.z;
        s3 += xv.x * w0.w + xv.y * w1.w + xv.z * w2.w + xv.w * w3.w;
    }
    part[tl][sg][0] = s0; part[tl][sg][1] = s1; part[tl][sg][2] = s2; part[tl][sg][3] = s3;
    __syncthreads();
    if (threadIdx.x < 64) {
        int tl2 = threadIdx.x >> 2, h = threadIdx.x & 3;
        float s = 0.f;
        #pragma unroll
        for (int g = 0; g < 16; g++) s += part[tl2][g][h];
        beta[(size_t)(blockIdx.x * 16 + tl2) * 4 + h] = 1.f / (1.f + __expf(-s));
    }
}

// ---------------- bf16 MFMA GEMM: C[M][N] = A[M][K] * BT[N][K]^T ----------------
template<int OUT_F32>
__global__ __launch_bounds__(256) void gemm_bt(
    const unsigned short* __restrict__ A, const unsigned short* __restrict__ BT,
    void* __restrict__ C, int M, int N, int K)
{
    __shared__ unsigned short As[128][40];
    __shared__ unsigned short Bs[128][40];
    int tid = threadIdx.x;
    int wave = tid >> 6, lane = tid & 63;
    int wr = (wave >> 1) * 64, wc = (wave & 1) * 64;
    int fr = lane & 15, fq = lane >> 4;
    int m0 = blockIdx.x * 128, n0 = blockIdx.y * 128;

    f32x4 acc[4][4];
    #pragma unroll
    for (int i = 0; i < 4; i++)
        #pragma unroll
        for (int j = 0; j < 4; j++) acc[i][j] = (f32x4){0.f, 0.f, 0.f, 0.f};

    for (int k0 = 0; k0 < K; k0 += 32) {
        #pragma unroll
        for (int r = 0; r < 2; r++) {
            int idx = tid + r * 256;
            int row = idx >> 2, c4 = idx & 3;
            const unsigned short* ga = &A[(size_t)(m0 + row) * K + k0 + c4 * 8];
            *(short8v*)&As[row][c4 * 8] = *(const short8v*)ga;
            const unsigned short* gb = &BT[(size_t)(n0 + row) * K + k0 + c4 * 8];
            *(short8v*)&Bs[row][c4 * 8] = *(const short8v*)gb;
        }
        __syncthreads();
        short8v a[4], b[4];
        #pragma unroll
        for (int i = 0; i < 4; i++) {
            a[i] = *(const short8v*)&As[wr + i * 16 + fr][fq * 8];
            b[i] = *(const short8v*)&Bs[wc + i * 16 + fr][fq * 8];
        }
        #pragma unroll
        for (int i = 0; i < 4; i++)
            #pragma unroll
            for (int j = 0; j < 4; j++)
                acc[i][j] = __builtin_amdgcn_mfma_f32_16x16x32_bf16(a[i], b[j], acc[i][j], 0, 0, 0);
        __syncthreads();
    }
    #pragma unroll
    for (int i = 0; i < 4; i++)
        #pragma unroll
        for (int j = 0; j < 4; j++)
            #pragma unroll
            for (int t = 0; t < 4; t++) {
                int row = m0 + wr + i * 16 + fq * 4 + t;
                int col = n0 + wc + j * 16 + fr;
                float val = acc[i][j][t];
                if (OUT_F32) ((float*)C)[(size_t)row * N + col] = val;
                else ((unsigned short*)C)[(size_t)row * N + col] = f2bf(val);
            }
}

// ---------------- per-chunk precompute (MFMA + 1-wave substitution) ----------------
// Outputs: Wbuf [t][128] = T'K, Ubuf [t][256] = T'V, Pbuf [t][64] = SC*tril(QK^T),
// KTbuf [d][t] normalized K^T.  T' = (I+A)^{-1} diag(beta), A = strict_tril(b KK^T).
__global__ __launch_bounds__(256) void chunk_pre(
    const unsigned short* __restrict__ QKVG, const float* __restrict__ beta,
    unsigned short* __restrict__ Wbuf, unsigned short* __restrict__ Ubuf,
    unsigned short* __restrict__ Pbuf, unsigned short* __restrict__ KTbuf)
{
    __shared__ unsigned short Ks[8192];   // [64][128] sw16 (normalized K)
    __shared__ unsigned short KTs[8192];  // [128][64] sw8
    __shared__ unsigned short VT[8192];   // [128][64] sw8 (half of V^T at a time)
    __shared__ unsigned short Tb[4096];   // [64][64] sw8  (T' bf16)
    __shared__ float Af[64][64];
    __shared__ float betas[64];

    int c = blockIdx.x, bh = blockIdx.y;
    int b = bh >> 2, h = bh & 3;
    int tid = threadIdx.x;
    int wv = tid >> 6, ln = tid & 63;
    int fr = ln & 15, fq = ln >> 4;
    int tok0 = b * SEQ + c * 64;
    size_t cb = (size_t)bh * NCHUNK + c;

    // phase 0: stage raw K rows -> Ks, betas
    #pragma unroll
    for (int r = 0; r < 4; r++) {
        int idx = tid + 256 * r;          // 0..1023
        int t = idx >> 4, u = idx & 15;
        short8v kv = *(const short8v*)(QKVG + (size_t)(tok0 + t) * NPROJ + 512 + h * 128 + u * 8);
        *(short8v*)(Ks + sw16(t, u * 8)) = kv;
    }
    if (tid < 64) betas[tid] = beta[(size_t)(tok0 + tid) * 4 + h];
    __syncthreads();

    // phase 1: L2-normalize rows of Ks (4 threads per row)
    {
        int t = tid >> 2, p = tid & 3;
        short8v v[4];
        float ss = 0.f;
        #pragma unroll
        for (int uu = 0; uu < 4; uu++) {
            v[uu] = *(const short8v*)(Ks + sw16(t, (p * 4 + uu) * 8));
            #pragma unroll
            for (int e = 0; e < 8; e++) {
                float f = bf2f((unsigned short)v[uu][e]);
                ss += f * f;
            }
        }
        ss += __shfl_xor(ss, 1);
        ss += __shfl_xor(ss, 2);
        float rn = rsqrtf(ss + 1e-12f);
        #pragma unroll
        for (int uu = 0; uu < 4; uu++) {
            short8v o;
            #pragma unroll
            for (int e = 0; e < 8; e++)
                o[e] = (short)f2bf(bf2f((unsigned short)v[uu][e]) * rn);
            *(short8v*)(Ks + sw16(t, (p * 4 + uu) * 8)) = o;
        }
    }
    __syncthreads();

    // phase 2: A = strict_tril(beta_t * K K^T) -> Af (f32)
    {
        f32x4 aacc[4];
        #pragma unroll
        for (int jt = 0; jt < 4; jt++) aacc[jt] = (f32x4){0.f, 0.f, 0.f, 0.f};
        #pragma unroll
        for (int ks = 0; ks < 4; ks++) {
            short8v ak = *(const short8v*)(Ks + sw16(16 * wv + fr, 32 * ks + 8 * fq));
            #pragma unroll
            for (int jt = 0; jt < 4; jt++) {
                short8v bk = *(const short8v*)(Ks + sw16(16 * jt + fr, 32 * ks + 8 * fq));
                aacc[jt] = __builtin_amdgcn_mfma_f32_16x16x32_bf16(ak, bk, aacc[jt], 0, 0, 0);
            }
        }
        #pragma unroll
        for (int jt = 0; jt < 4; jt++)
            #pragma unroll
            for (int r = 0; r < 4; r++) {
                int t = 16 * wv + 4 * fq + r, s = 16 * jt + fr;
                if (s < t) Af[t][s] = betas[t] * aacc[jt][r];
            }
    }
    __syncthreads();

    // phase 3: wave0 computes T=(I+A)^{-1} in-place (strict lower of Af);
    //          waves 1-3 build K^T and V^T(half0) scatters.
    if (wv == 0) {
        int cc = ln;   // column
        for (int t = 1; t < 64; t++) {
            float aown = Af[t][cc];
            float acc = 0.f;
            for (int s = cc + 1; s < t; s++)
                acc += Af[t][s] * Af[s][cc];
            if (cc < t) Af[t][cc] = -aown - acc;
        }
    } else {
        int q = tid - 64;   // 0..191
        for (int g = q; g < 1024; g += 192) {
            int t = g >> 4, u = g & 15;
            short8v kv = *(const short8v*)(Ks + sw16(t, u * 8));
            #pragma unroll
            for (int e = 0; e < 8; e++)
                KTs[sw8(u * 8 + e, t)] = (unsigned short)kv[e];
        }
        for (int g = q; g < 1024; g += 192) {
            int t = g >> 4, jg = g & 15;
            short8v vv = *(const short8v*)(QKVG + (size_t)(tok0 + t) * NPROJ + 1024 + h * 256 + jg * 8);
            #pragma unroll
            for (int e = 0; e < 8; e++)
                VT[sw8(jg * 8 + e, t)] = (unsigned short)vv[e];
        }
    }
    __syncthreads();

    // phase 4: P = SC*tril(Q K^T) (Q read from global), Tb = T*diag(beta) bf16, KT -> global
    {
        f32x4 pacc[4];
        #pragma unroll
        for (int jt = 0; jt < 4; jt++) pacc[jt] = (f32x4){0.f, 0.f, 0.f, 0.f};
        #pragma unroll
        for (int ks = 0; ks < 4; ks++) {
            short8v aq = *(const short8v*)(QKVG + (size_t)(tok0 + 16 * wv + fr) * NPROJ + h * 128 + ks * 32 + fq * 8);
            #pragma unroll
            for (int jt = 0; jt < 4; jt++) {
                short8v bk = *(const short8v*)(Ks + sw16(16 * jt + fr, 32 * ks + 8 * fq));
                pacc[jt] = __builtin_amdgcn_mfma_f32_16x16x32_bf16(aq, bk, pacc[jt], 0, 0, 0);
            }
        }
        #pragma unroll
        for (int jt = 0; jt < 4; jt++)
            #pragma unroll
            for (int r = 0; r < 4; r++) {
                int t = 16 * wv + 4 * fq + r, s = 16 * jt + fr;
                float val = (s <= t) ? pacc[jt][r] * SCQ : 0.f;
                Pbuf[cb * 4096 + t * 64 + s] = f2bf(val);
            }
        #pragma unroll
        for (int i = 0; i < 16; i++) {
            int idx = tid + 256 * i;   // 0..4095
            int t = idx >> 6, s = idx & 63;
            float tv = (s < t) ? Af[t][s] : (s == t ? 1.f : 0.f);
            Tb[sw8(t, s)] = f2bf(tv * betas[s]);
        }
        #pragma unroll
        for (int i = 0; i < 4; i++) {
            int idx = tid + 256 * i;   // 0..1023
            int d = idx >> 3, ug = idx & 7;
            *(short8v*)(KTbuf + cb * 8192 + (size_t)d * 64 + ug * 8) =
                *(const short8v*)(KTs + sw8(d, ug * 8));
        }
    }
    __syncthreads();

    // phase 5: W = T'K (via KTs), U half0 = T'V[:,0:128] (via VT)
    {
        f32x4 wacc[8], uacc[8];
        #pragma unroll
        for (int jt = 0; jt < 8; jt++) {
            wacc[jt] = (f32x4){0.f, 0.f, 0.f, 0.f};
            uacc[jt] = (f32x4){0.f, 0.f, 0.f, 0.f};
        }
        #pragma unroll
        for (int ks = 0; ks < 2; ks++) {
            short8v at = *(const short8v*)(Tb + sw8(16 * wv + fr, 32 * ks + 8 * fq));
            #pragma unroll
            for (int jt = 0; jt < 8; jt++) {
                short8v bk = *(const short8v*)(KTs + sw8(16 * jt + fr, 32 * ks + 8 * fq));
                wacc[jt] = __builtin_amdgcn_mfma_f32_16x16x32_bf16(at, bk, wacc[jt], 0, 0, 0);
                short8v bv = *(const short8v*)(VT + sw8(16 * jt + fr, 32 * ks + 8 * fq));
                uacc[jt] = __builtin_amdgcn_mfma_f32_16x16x32_bf16(at, bv, uacc[jt], 0, 0, 0);
            }
        }
        #pragma unroll
        for (int jt = 0; jt < 8; jt++)
            #pragma unroll
            for (int r = 0; r < 4; r++) {
                int t = 16 * wv + 4 * fq + r, d = 16 * jt + fr;
                Wbuf[cb * 8192 + (size_t)t * 128 + d] = f2bf(wacc[jt][r]);
                Ubuf[cb * 16384 + (size_t)t * 256 + d] = f2bf(uacc[jt][r]);
            }
    }
    __syncthreads();

    // phase 6: restage VT with half1, then U half1
    #pragma unroll
    for (int i = 0; i < 4; i++) {
        int g = tid + 256 * i;   // 0..1023
        int t = g >> 4, jg = g & 15;
        short8v vv = *(const short8v*)(QKVG + (size_t)(tok0 + t) * NPROJ + 1024 + h * 256 + 128 + jg * 8);
        #pragma unroll
        for (int e = 0; e < 8; e++)
            VT[sw8(jg * 8 + e, t)] = (unsigned short)vv[e];
    }
    __syncthreads();
    {
        f32x4 uacc[8];
        #pragma unroll
        for (int jt = 0; jt < 8; jt++) uacc[jt] = (f32x4){0.f, 0.f, 0.f, 0.f};
        #pragma unroll
        for (int ks = 0; ks < 2; ks++) {
            short8v at = *(const short8v*)(Tb + sw8(16 * wv + fr, 32 * ks + 8 * fq));
            #pragma unroll
            for (int jt = 0; jt < 8; jt++) {
                short8v bv = *(const short8v*)(VT + sw8(16 * jt + fr, 32 * ks + 8 * fq));
                uacc[jt] = __builtin_amdgcn_mfma_f32_16x16x32_bf16(at, bv, uacc[jt], 0, 0, 0);
            }
        }
        #pragma unroll
        for (int jt = 0; jt < 8; jt++)
            #pragma unroll
            for (int r = 0; r < 4; r++) {
                int t = 16 * wv + 4 * fq + r, j = 16 * jt + fr;
                Ubuf[cb * 16384 + (size_t)t * 256 + 128 + j] = f2bf(uacc[jt][r]);
            }
    }
}

// ---------------- MFMA chunk scan ----------------
// grid (4 dv-slices, 8 bh), 256 threads. State S[128][64] f32 in MFMA accumulators.
#define SBUF   32896
#define SW_OFF 0
#define SQ_OFF 8192
#define SKT_OFF 16384
#define SP_OFF 24576
#define SU_OFF 28672
#define SST_OFF (2 * SBUF)
#define SDT_OFF (2 * SBUF + 8192)

__global__ __launch_bounds__(256, 1) void scan_mfma(
    const unsigned short* __restrict__ QKVG, const unsigned short* __restrict__ Wbuf,
    const unsigned short* __restrict__ Ubuf, const unsigned short* __restrict__ Pbuf,
    const unsigned short* __restrict__ KTbuf, unsigned short* __restrict__ Ob)
{
    extern __shared__ unsigned short lds[];
    int tid = threadIdx.x;
    int wv = tid >> 6, ln = tid & 63;
    int fr = ln & 15, fq = ln >> 4;
    int j0 = blockIdx.x * 64;
    int bh = blockIdx.y;
    int b = bh >> 2, h = bh & 3;

    unsigned short* ST = lds + SST_OFF;
    unsigned short* DT = lds + SDT_OFF;

    f32x4 sacc[2][4];
    #pragma unroll
    for (int i = 0; i < 2; i++)
        #pragma unroll
        for (int j = 0; j < 4; j++) sacc[i][j] = (f32x4){0.f, 0.f, 0.f, 0.f};

    short8v rg[16];
    auto issue = [&](int c1) {
        size_t cb = (size_t)bh * NCHUNK + c1;
        const unsigned short* Wc = Wbuf + cb * (64 * 128);
        const unsigned short* Uc = Ubuf + cb * (64 * 256);
        const unsigned short* Pc = Pbuf + cb * (64 * 64);
        const unsigned short* Kc = KTbuf + cb * (128 * 64);
        int tok0 = b * SEQ + c1 * 64;
        #pragma unroll
        for (int i = 0; i < 4; i++) {
            int p = tid + 256 * i;
            int t = p >> 4, up = p & 15;
            int u = (up & 8) | ((up ^ t) & 7);
            rg[i] = *(const short8v*)(Wc + t * 128 + u * 8);
            rg[4 + i] = *(const short8v*)(QKVG + (size_t)(tok0 + t) * NPROJ + h * 128 + u * 8);
            int d = p >> 3;
            int u8 = (p ^ d) & 7;
            rg[8 + i] = *(const short8v*)(Kc + d * 64 + u8 * 8);
        }
        #pragma unroll
        for (int i = 0; i < 2; i++) {
            int p = tid + 256 * i;
            int t = p >> 3;
            int u8 = (p ^ t) & 7;
            rg[12 + i] = *(const short8v*)(Pc + t * 64 + u8 * 8);
            rg[14 + i] = *(const short8v*)(Uc + t * 256 + j0 + (p & 7) * 8);
        }
    };
    auto commit = [&](unsigned short* bb) {
        #pragma unroll
        for (int i = 0; i < 4; i++) {
            int p = tid + 256 * i;
            *(short8v*)(bb + SW_OFF + p * 8) = rg[i];
            *(short8v*)(bb + SQ_OFF + p * 8) = rg[4 + i];
            *(short8v*)(bb + SKT_OFF + p * 8) = rg[8 + i];
        }
        #pragma unroll
        for (int i = 0; i < 2; i++) {
            int p = tid + 256 * i;
            *(short8v*)(bb + SP_OFF + p * 8) = rg[12 + i];
            *(short8v*)(bb + SU_OFF + (p >> 3) * 66 + (p & 7) * 8) = rg[14 + i];
        }
    };

    issue(0);
    commit(lds);
    __syncthreads();

    for (int c = 0; c < NCHUNK; c++) {
        unsigned short* ba = (c & 1) ? (lds + SBUF) : lds;
        unsigned short* bb = (c & 1) ? lds : (lds + SBUF);
        if (c < NCHUNK - 1) issue(c + 1);

        // dump state S -> ST[j][d] bf16 (swizzled)
        #pragma unroll
        for (int dtt = 0; dtt < 2; dtt++)
            #pragma unroll
            for (int jt = 0; jt < 4; jt++) {
                int d0 = 32 * wv + 16 * dtt + 4 * fq;
                int j = 16 * jt + fr;
                f32x4 v = sacc[dtt][jt];
                unsigned int lo = f2bf(v[0]) | ((unsigned)f2bf(v[1]) << 16);
                unsigned int hi = f2bf(v[2]) | ((unsigned)f2bf(v[3]) << 16);
                *(uint2*)&ST[sw16(j, d0)] = make_uint2(lo, hi);
            }
        __syncthreads();

        // merged: dacc = W*S, oacc = Q*S  (wave owns t-band 16*wv)
        f32x4 dacc[4], oacc[4];
        #pragma unroll
        for (int jt = 0; jt < 4; jt++) {
            dacc[jt] = (f32x4){0.f, 0.f, 0.f, 0.f};
            oacc[jt] = (f32x4){0.f, 0.f, 0.f, 0.f};
        }
        #pragma unroll
        for (int ks = 0; ks < 4; ks++) {
            short8v aw = *(const short8v*)(ba + SW_OFF + sw16(16 * wv + fr, 32 * ks + 8 * fq));
            short8v aq = *(const short8v*)(ba + SQ_OFF + sw16(16 * wv + fr, 32 * ks + 8 * fq));
            #pragma unroll
            for (int jt = 0; jt < 4; jt++) {
                short8v bs = *(const short8v*)(ST + sw16(16 * jt + fr, 32 * ks + 8 * fq));
                dacc[jt] = __builtin_amdgcn_mfma_f32_16x16x32_bf16(aw, bs, dacc[jt], 0, 0, 0);
                oacc[jt] = __builtin_amdgcn_mfma_f32_16x16x32_bf16(aq, bs, oacc[jt], 0, 0, 0);
            }
        }
        // scale the Q*S contribution by 128^-0.5 (Q is raw; P already folds SC)
        #pragma unroll
        for (int jt = 0; jt < 4; jt++) oacc[jt] *= SCQ;
        // Delta = U - dacc -> DT[j][t] bf16 (swizzled)
        #pragma unroll
        for (int jt = 0; jt < 4; jt++) {
            int j = 16 * jt + fr;
            int t0 = 16 * wv + 4 * fq;
            float v0 = bf2f(ba[SU_OFF + (t0 + 0) * 66 + j]) - dacc[jt][0];
            float v1 = bf2f(ba[SU_OFF + (t0 + 1) * 66 + j]) - dacc[jt][1];
            float v2 = bf2f(ba[SU_OFF + (t0 + 2) * 66 + j]) - dacc[jt][2];
            float v3 = bf2f(ba[SU_OFF + (t0 + 3) * 66 + j]) - dacc[jt][3];
            unsigned int lo = f2bf(v0) | ((unsigned)f2bf(v1) << 16);
            unsigned int hi = f2bf(v2) | ((unsigned)f2bf(v3) << 16);
            *(uint2*)&DT[sw8(j, t0)] = make_uint2(lo, hi);
        }
        __syncthreads();

        // oacc += P * Delta
        #pragma unroll
        for (int ks = 0; ks < 2; ks++) {
            short8v ap = *(const short8v*)(ba + SP_OFF + sw8(16 * wv + fr, 32 * ks + 8 * fq));
            #pragma unroll
            for (int jt = 0; jt < 4; jt++) {
                short8v bd = *(const short8v*)(DT + sw8(16 * jt + fr, 32 * ks + 8 * fq));
                oacc[jt] = __builtin_amdgcn_mfma_f32_16x16x32_bf16(ap, bd, oacc[jt], 0, 0, 0);
            }
        }
        // S += K^T * Delta  (wave owns d-band 32*wv)
        #pragma unroll
        for (int ks = 0; ks < 2; ks++) {
            short8v ak0 = *(const short8v*)(ba + SKT_OFF + sw8(32 * wv + fr, 32 * ks + 8 * fq));
            short8v ak1 = *(const short8v*)(ba + SKT_OFF + sw8(32 * wv + 16 + fr, 32 * ks + 8 * fq));
            #pragma unroll
            for (int jt = 0; jt < 4; jt++) {
                short8v bd = *(const short8v*)(DT + sw8(16 * jt + fr, 32 * ks + 8 * fq));
                sacc[0][jt] = __builtin_amdgcn_mfma_f32_16x16x32_bf16(ak0, bd, sacc[0][jt], 0, 0, 0);
                sacc[1][jt] = __builtin_amdgcn_mfma_f32_16x16x32_bf16(ak1, bd, sacc[1][jt], 0, 0, 0);
            }
        }
        // O store
        int tok0 = b * SEQ + c * 64;
        #pragma unroll
        for (int jt = 0; jt < 4; jt++)
            #pragma unroll
            for (int r = 0; r < 4; r++) {
                int t = 16 * wv + 4 * fq + r;
                Ob[(size_t)(tok0 + t) * 1024 + h * 256 + j0 + 16 * jt + fr] = f2bf(oacc[jt][r]);
            }
        if (c < NCHUNK - 1) commit(bb);
        __syncthreads();
    }
}

// ---------------- RMSNorm + swish gate ----------------
__global__ void gate_norm(const unsigned short* __restrict__ Ob,
                          const unsigned short* __restrict__ QKVG,
                          const float* __restrict__ norm_w,
                          unsigned short* __restrict__ o2)
{
    __shared__ float red[4];
    int tok = blockIdx.x >> 2, h = blockIdx.x & 3;
    int j = threadIdx.x;
    float o = bf2f(Ob[(size_t)tok * 1024 + h * 256 + j]);
    float ss = o * o;
    #pragma unroll
    for (int off = 32; off; off >>= 1) ss += __shfl_xor(ss, off);
    if ((threadIdx.x & 63) == 0) red[threadIdx.x >> 6] = ss;
    __syncthreads();
    float tot = red[0] + red[1] + red[2] + red[3];
    float r = rsqrtf(tot * (1.0f / 256.0f) + 1e-5f);
    float g = bf2f(QKVG[(size_t)tok * NPROJ + 2048 + h * 256 + j]);
    float sw = g / (1.f + __expf(-g));
    o2[(size_t)tok * 1024 + h * 256 + j] = f2bf(o * r * norm_w[j] * sw);
}

// ---------------- launch ----------------
extern "C" void kernel_launch(void* const* d_in, const int* in_sizes, int n_in,
                              void* d_out, int out_size, void* d_ws, size_t ws_size,
                              hipStream_t stream) {
    const float* x      = (const float*)d_in[0];
    const float* Wq     = (const float*)d_in[1];
    const float* Wk     = (const float*)d_in[2];
    const float* Wv     = (const float*)d_in[3];
    const float* Wb     = (const float*)d_in[4];
    const float* Wg     = (const float*)d_in[5];
    const float* Wo     = (const float*)d_in[6];
    const float* norm_w = (const float*)d_in[7];
    float* out = (float*)d_out;

    char* ws = (char*)d_ws;
    unsigned short* xb   = (unsigned short*)(ws + 0);          // 16,777,216
    unsigned short* KTbuf= (unsigned short*)(ws + 0);          // aliases xb (dead after gemm<0>)
    unsigned short* WT   = (unsigned short*)(ws + 16777216);   //  6,291,456
    unsigned short* WoT  = (unsigned short*)(ws + 23068672);   //  2,097,152
    unsigned short* QKVG = (unsigned short*)(ws + 25165824);   // 50,331,648
    float*          beta = (float*)        (ws + 75497472);    //    131,072
    unsigned short* Wbuf = (unsigned short*)(ws + 75628544);   //  8,388,608
    unsigned short* Ubuf = (unsigned short*)(ws + 84017152);   // 16,777,216
    unsigned short* Pbuf = (unsigned short*)(ws + 100794368);  //  4,194,304
    unsigned short* Ob   = (unsigned short*)(ws + 104988672);  // 16,777,216
    unsigned short* o2   = (unsigned short*)(ws + 121765888);  // 16,777,216

    (void)hipFuncSetAttribute((const void*)scan_mfma,
                              hipFuncAttributeMaxDynamicSharedMemorySize, 156160);

    convert_x<<<(NTOK * DM + 255) / 256, 256, 0, stream>>>(x, xb, NTOK * DM);
    build_wt<<<(NPROJ * DM + 255) / 256, 256, 0, stream>>>(Wq, Wk, Wv, Wg, WT);
    build_wot<<<(DM * DM + 255) / 256, 256, 0, stream>>>(Wo, WoT);
    beta_kernel<<<NTOK / 16, 256, 0, stream>>>(x, Wb, beta);
    gemm_bt<0><<<dim3(64, 24), 256, 0, stream>>>(xb, WT, (void*)QKVG, NTOK, NPROJ, DM);
    chunk_pre<<<dim3(NCHUNK, 8), 256, 0, stream>>>(QKVG, beta, Wbuf, Ubuf, Pbuf, KTbuf);
    scan_mfma<<<dim3(4, 8), 256, 156160, stream>>>(QKVG, Wbuf, Ubuf, Pbuf, KTbuf, Ob);
    gate_norm<<<NTOK * 4, 256, 0, stream>>>(Ob, QKVG, norm_w, o2);
    gemm_bt<1><<<dim3(64, 8), 256, 0, stream>>>(o2, WoT, (void*)out, NTOK, DM, DM);
}

// Round 4
// 425.822 us; speedup vs baseline: 7.3466x; 1.0579x over previous
//
#include <hip/hip_runtime.h>
#include <hip/hip_bf16.h>
#include <stdint.h>
#include <stddef.h>

typedef __attribute__((ext_vector_type(8))) short short8v;  // 8 bf16 = 4 VGPR
typedef __attribute__((ext_vector_type(4))) float f32x4;

__device__ __forceinline__ float bf2f(unsigned short u) {
    return __uint_as_float(((unsigned int)u) << 16);
}
__device__ __forceinline__ unsigned short f2bf(float f) {
    unsigned int x = __float_as_uint(f);
    x += 0x7fffu + ((x >> 16) & 1u);   // RNE
    return (unsigned short)(x >> 16);
}

#define NTOK 8192      // b*n
#define DM   1024
#define NPROJ 3072     // q512 | k512 | v1024 | g1024
#define SEQ  4096
#define NCHUNK 64      // chunks per sequence (4096/64)
#define SCQ 0.08838834764831845f   // 128^-0.5

// async global->LDS, 16B per lane, wave-uniform LDS base (linear dest only!)
#define GLDS16(g, l) __builtin_amdgcn_global_load_lds( \
    (const __attribute__((address_space(1))) void*)(g), \
    (__attribute__((address_space(3))) void*)(l), 16, 0, 0)

// barrier that does NOT drain vmcnt (prefetch loads / stores stay in flight)
__device__ __forceinline__ void bar_lgkm() {
    asm volatile("s_waitcnt lgkmcnt(0)" ::: "memory");
    __builtin_amdgcn_s_barrier();
    __builtin_amdgcn_sched_barrier(0);
}

// swizzled LDS element offsets (2B elems). 256B rows (16 units of 16B):
__device__ __forceinline__ int sw16(int row, int k) {
    int u = k >> 3;
    int us = (u & 8) | ((u ^ row) & 7);
    return row * 128 + us * 8 + (k & 7);
}
// 128B rows (8 units):
__device__ __forceinline__ int sw8(int row, int k) {
    int u = k >> 3;
    int us = (u ^ row) & 7;
    return row * 64 + us * 8 + (k & 7);
}

// ---------------- elementwise / conversion ----------------
__global__ void convert_x(const float* __restrict__ x, unsigned short* __restrict__ xb, int n) {
    int i = blockIdx.x * 256 + threadIdx.x;
    if (i < n) xb[i] = f2bf(x[i]);
}

__global__ void build_wt(const float* __restrict__ Wq, const float* __restrict__ Wk,
                         const float* __restrict__ Wv, const float* __restrict__ Wg,
                         unsigned short* __restrict__ WT) {
    int i = blockIdx.x * 256 + threadIdx.x;   // WT[n][kk] = W(kk,n)
    if (i >= NPROJ * DM) return;
    int n = i >> 10, kk = i & 1023;
    float v;
    if (n < 512)       v = Wq[kk * 512 + n];
    else if (n < 1024) v = Wk[kk * 512 + (n - 512)];
    else if (n < 2048) v = Wv[kk * 1024 + (n - 1024)];
    else               v = Wg[kk * 1024 + (n - 2048)];
    WT[i] = f2bf(v);
}

__global__ void build_wot(const float* __restrict__ Wo, unsigned short* __restrict__ WoT) {
    int i = blockIdx.x * 256 + threadIdx.x;   // WoT[n][kk] = Wo[kk][n]
    if (i >= DM * DM) return;
    int n = i >> 10, kk = i & 1023;
    WoT[i] = f2bf(Wo[kk * 1024 + n]);
}

// beta: block handles 16 tokens; 16 seg-threads per token, float4 loads.
__global__ __launch_bounds__(256) void beta_kernel(const float* __restrict__ x,
                                                   const float* __restrict__ Wb,
                                                   float* __restrict__ beta) {
    __shared__ float part[16][16][4];
    int tl = threadIdx.x >> 4, sg = threadIdx.x & 15;
    int tok = blockIdx.x * 16 + tl;
    const float4* xr = (const float4*)(x + (size_t)tok * DM);
    const float4* wb = (const float4*)Wb;
    float s0 = 0.f, s1 = 0.f, s2 = 0.f, s3 = 0.f;
    #pragma unroll
    for (int it = 0; it < 16; it++) {
        int f = it * 16 + sg;
        float4 xv = xr[f];
        float4 w0 = wb[4 * f + 0], w1 = wb[4 * f + 1], w2 = wb[4 * f + 2], w3 = wb[4 * f + 3];
        s0 += xv.x * w0.x + xv.y * w1.x + xv.z * w2.x + xv.w * w3.x;
        s1 += xv.x * w0.y + xv.y * w1.y + xv.z * w2.y + xv.w * w3.y;
        s2 += xv.x * w0.z + xv.y * w1.z + xv.z * w2.z + xv.w * w3.z;
        s3 += xv.x * w0.w + xv.y * w1.w + xv.z * w2.w + xv.w * w3.w;
    }
    part[tl][sg][0] = s0; part[tl][sg][1] = s1; part[tl][sg][2] = s2; part[tl][sg][3] = s3;
    __syncthreads();
    if (threadIdx.x < 64) {
        int tl2 = threadIdx.x >> 2, h = threadIdx.x & 3;
        float s = 0.f;
        #pragma unroll
        for (int g = 0; g < 16; g++) s += part[tl2][g][h];
        beta[(size_t)(blockIdx.x * 16 + tl2) * 4 + h] = 1.f / (1.f + __expf(-s));
    }
}

// ---------------- bf16 MFMA GEMM: C[M][N] = A[M][K] * BT[N][K]^T ----------------
// 128x128 tile, BK=32, 4 waves, global_load_lds width-16 staging (linear LDS).
template<int OUT_F32>
__global__ __launch_bounds__(256) void gemm_bt(
    const unsigned short* __restrict__ A, const unsigned short* __restrict__ BT,
    void* __restrict__ C, int M, int N, int K)
{
    __shared__ unsigned short As[128][32];   // linear (gload_lds requires no pad)
    __shared__ unsigned short Bs[128][32];
    int tid = threadIdx.x;
    int wave = tid >> 6, lane = tid & 63;
    int wr = (wave >> 1) * 64, wc = (wave & 1) * 64;
    int fr = lane & 15, fq = lane >> 4;
    int m0 = blockIdx.x * 128, n0 = blockIdx.y * 128;

    f32x4 acc[4][4];
    #pragma unroll
    for (int i = 0; i < 4; i++)
        #pragma unroll
        for (int j = 0; j < 4; j++) acc[i][j] = (f32x4){0.f, 0.f, 0.f, 0.f};

    int srow = (lane >> 2);        // 0..15 within 16-row segment
    int sce  = (lane & 3) * 8;     // col element 0,8,16,24

    for (int k0 = 0; k0 < K; k0 += 32) {
        #pragma unroll
        for (int i = 0; i < 2; i++) {
            int seg = wave * 2 + i;               // 0..7 : rows [seg*16, seg*16+16)
            int row = seg * 16 + srow;
            GLDS16(&A[(size_t)(m0 + row) * K + k0 + sce], &As[0][0] + seg * 512);
            GLDS16(&BT[(size_t)(n0 + row) * K + k0 + sce], &Bs[0][0] + seg * 512);
        }
        __syncthreads();   // full drain: gload_lds must land (m97 structure)
        short8v a[4], b[4];
        #pragma unroll
        for (int i = 0; i < 4; i++) {
            a[i] = *(const short8v*)&As[wr + i * 16 + fr][fq * 8];
            b[i] = *(const short8v*)&Bs[wc + i * 16 + fr][fq * 8];
        }
        #pragma unroll
        for (int i = 0; i < 4; i++)
            #pragma unroll
            for (int j = 0; j < 4; j++)
                acc[i][j] = __builtin_amdgcn_mfma_f32_16x16x32_bf16(a[i], b[j], acc[i][j], 0, 0, 0);
        __syncthreads();
    }
    #pragma unroll
    for (int i = 0; i < 4; i++)
        #pragma unroll
        for (int j = 0; j < 4; j++)
            #pragma unroll
            for (int t = 0; t < 4; t++) {
                int row = m0 + wr + i * 16 + fq * 4 + t;
                int col = n0 + wc + j * 16 + fr;
                float val = acc[i][j][t];
                if (OUT_F32) ((float*)C)[(size_t)row * N + col] = val;
                else ((unsigned short*)C)[(size_t)row * N + col] = f2bf(val);
            }
}

// ---------------- per-chunk precompute (MFMA + 1-wave substitution) ----------------
// Outputs: Wbuf [t][128] = -T'K (NEGATED), Ubuf [t][256] = T'V, Pbuf [t][64] = SC*tril(QK^T),
// KTbuf [d][t] normalized K^T.  T' = (I+A)^{-1} diag(beta), A = strict_tril(b KK^T).
__global__ __launch_bounds__(256) void chunk_pre(
    const unsigned short* __restrict__ QKVG, const float* __restrict__ beta,
    unsigned short* __restrict__ Wbuf, unsigned short* __restrict__ Ubuf,
    unsigned short* __restrict__ Pbuf, unsigned short* __restrict__ KTbuf)
{
    __shared__ unsigned short Ks[8192];   // [64][128] sw16 (normalized K)
    __shared__ unsigned short KTs[8192];  // [128][64] sw8
    __shared__ unsigned short VT[8192];   // [128][64] sw8 (half of V^T at a time)
    __shared__ unsigned short Tb[4096];   // [64][64] sw8  (T' bf16)
    __shared__ float Af[64][64];
    __shared__ float betas[64];

    int c = blockIdx.x, bh = blockIdx.y;
    int b = bh >> 2, h = bh & 3;
    int tid = threadIdx.x;
    int wv = tid >> 6, ln = tid & 63;
    int fr = ln & 15, fq = ln >> 4;
    int tok0 = b * SEQ + c * 64;
    size_t cb = (size_t)bh * NCHUNK + c;

    // phase 0: stage raw K rows -> Ks, betas
    #pragma unroll
    for (int r = 0; r < 4; r++) {
        int idx = tid + 256 * r;          // 0..1023
        int t = idx >> 4, u = idx & 15;
        short8v kv = *(const short8v*)(QKVG + (size_t)(tok0 + t) * NPROJ + 512 + h * 128 + u * 8);
        *(short8v*)(Ks + sw16(t, u * 8)) = kv;
    }
    if (tid < 64) betas[tid] = beta[(size_t)(tok0 + tid) * 4 + h];
    __syncthreads();

    // phase 1: L2-normalize rows of Ks (4 threads per row)
    {
        int t = tid >> 2, p = tid & 3;
        short8v v[4];
        float ss = 0.f;
        #pragma unroll
        for (int uu = 0; uu < 4; uu++) {
            v[uu] = *(const short8v*)(Ks + sw16(t, (p * 4 + uu) * 8));
            #pragma unroll
            for (int e = 0; e < 8; e++) {
                float f = bf2f((unsigned short)v[uu][e]);
                ss += f * f;
            }
        }
        ss += __shfl_xor(ss, 1);
        ss += __shfl_xor(ss, 2);
        float rn = rsqrtf(ss + 1e-12f);
        #pragma unroll
        for (int uu = 0; uu < 4; uu++) {
            short8v o;
            #pragma unroll
            for (int e = 0; e < 8; e++)
                o[e] = (short)f2bf(bf2f((unsigned short)v[uu][e]) * rn);
            *(short8v*)(Ks + sw16(t, (p * 4 + uu) * 8)) = o;
        }
    }
    __syncthreads();

    // phase 2: A = strict_tril(beta_t * K K^T) -> Af (f32)
    {
        f32x4 aacc[4];
        #pragma unroll
        for (int jt = 0; jt < 4; jt++) aacc[jt] = (f32x4){0.f, 0.f, 0.f, 0.f};
        #pragma unroll
        for (int ks = 0; ks < 4; ks++) {
            short8v ak = *(const short8v*)(Ks + sw16(16 * wv + fr, 32 * ks + 8 * fq));
            #pragma unroll
            for (int jt = 0; jt < 4; jt++) {
                short8v bk = *(const short8v*)(Ks + sw16(16 * jt + fr, 32 * ks + 8 * fq));
                aacc[jt] = __builtin_amdgcn_mfma_f32_16x16x32_bf16(ak, bk, aacc[jt], 0, 0, 0);
            }
        }
        #pragma unroll
        for (int jt = 0; jt < 4; jt++)
            #pragma unroll
            for (int r = 0; r < 4; r++) {
                int t = 16 * wv + 4 * fq + r, s = 16 * jt + fr;
                if (s < t) Af[t][s] = betas[t] * aacc[jt][r];
            }
    }
    __syncthreads();

    // phase 3: wave0 computes T=(I+A)^{-1} in-place (strict lower of Af);
    //          waves 1-3 build K^T and V^T(half0) scatters.
    if (wv == 0) {
        int cc = ln;   // column
        for (int t = 1; t < 64; t++) {
            float aown = Af[t][cc];
            float acc = 0.f;
            for (int s = cc + 1; s < t; s++)
                acc += Af[t][s] * Af[s][cc];
            if (cc < t) Af[t][cc] = -aown - acc;
        }
    } else {
        int q = tid - 64;   // 0..191
        for (int g = q; g < 1024; g += 192) {
            int t = g >> 4, u = g & 15;
            short8v kv = *(const short8v*)(Ks + sw16(t, u * 8));
            #pragma unroll
            for (int e = 0; e < 8; e++)
                KTs[sw8(u * 8 + e, t)] = (unsigned short)kv[e];
        }
        for (int g = q; g < 1024; g += 192) {
            int t = g >> 4, jg = g & 15;
            short8v vv = *(const short8v*)(QKVG + (size_t)(tok0 + t) * NPROJ + 1024 + h * 256 + jg * 8);
            #pragma unroll
            for (int e = 0; e < 8; e++)
                VT[sw8(jg * 8 + e, t)] = (unsigned short)vv[e];
        }
    }
    __syncthreads();

    // phase 4: P = SC*tril(Q K^T) (Q read from global), Tb = T*diag(beta) bf16, KT -> global
    {
        f32x4 pacc[4];
        #pragma unroll
        for (int jt = 0; jt < 4; jt++) pacc[jt] = (f32x4){0.f, 0.f, 0.f, 0.f};
        #pragma unroll
        for (int ks = 0; ks < 4; ks++) {
            short8v aq = *(const short8v*)(QKVG + (size_t)(tok0 + 16 * wv + fr) * NPROJ + h * 128 + ks * 32 + fq * 8);
            #pragma unroll
            for (int jt = 0; jt < 4; jt++) {
                short8v bk = *(const short8v*)(Ks + sw16(16 * jt + fr, 32 * ks + 8 * fq));
                pacc[jt] = __builtin_amdgcn_mfma_f32_16x16x32_bf16(aq, bk, pacc[jt], 0, 0, 0);
            }
        }
        #pragma unroll
        for (int jt = 0; jt < 4; jt++)
            #pragma unroll
            for (int r = 0; r < 4; r++) {
                int t = 16 * wv + 4 * fq + r, s = 16 * jt + fr;
                float val = (s <= t) ? pacc[jt][r] * SCQ : 0.f;
                Pbuf[cb * 4096 + t * 64 + s] = f2bf(val);
            }
        #pragma unroll
        for (int i = 0; i < 16; i++) {
            int idx = tid + 256 * i;   // 0..4095
            int t = idx >> 6, s = idx & 63;
            float tv = (s < t) ? Af[t][s] : (s == t ? 1.f : 0.f);
            Tb[sw8(t, s)] = f2bf(tv * betas[s]);
        }
        #pragma unroll
        for (int i = 0; i < 4; i++) {
            int idx = tid + 256 * i;   // 0..1023
            int d = idx >> 3, ug = idx & 7;
            *(short8v*)(KTbuf + cb * 8192 + (size_t)d * 64 + ug * 8) =
                *(const short8v*)(KTs + sw8(d, ug * 8));
        }
    }
    __syncthreads();

    // phase 5: W = -(T'K) (via KTs), U half0 = T'V[:,0:128] (via VT)
    {
        f32x4 wacc[8], uacc[8];
        #pragma unroll
        for (int jt = 0; jt < 8; jt++) {
            wacc[jt] = (f32x4){0.f, 0.f, 0.f, 0.f};
            uacc[jt] = (f32x4){0.f, 0.f, 0.f, 0.f};
        }
        #pragma unroll
        for (int ks = 0; ks < 2; ks++) {
            short8v at = *(const short8v*)(Tb + sw8(16 * wv + fr, 32 * ks + 8 * fq));
            #pragma unroll
            for (int jt = 0; jt < 8; jt++) {
                short8v bk = *(const short8v*)(KTs + sw8(16 * jt + fr, 32 * ks + 8 * fq));
                wacc[jt] = __builtin_amdgcn_mfma_f32_16x16x32_bf16(at, bk, wacc[jt], 0, 0, 0);
                short8v bv = *(const short8v*)(VT + sw8(16 * jt + fr, 32 * ks + 8 * fq));
                uacc[jt] = __builtin_amdgcn_mfma_f32_16x16x32_bf16(at, bv, uacc[jt], 0, 0, 0);
            }
        }
        #pragma unroll
        for (int jt = 0; jt < 8; jt++)
            #pragma unroll
            for (int r = 0; r < 4; r++) {
                int t = 16 * wv + 4 * fq + r, d = 16 * jt + fr;
                Wbuf[cb * 8192 + (size_t)t * 128 + d] = f2bf(-wacc[jt][r]);   // NEGATED
                Ubuf[cb * 16384 + (size_t)t * 256 + d] = f2bf(uacc[jt][r]);
            }
    }
    __syncthreads();

    // phase 6: restage VT with half1, then U half1
    #pragma unroll
    for (int i = 0; i < 4; i++) {
        int g = tid + 256 * i;   // 0..1023
        int t = g >> 4, jg = g & 15;
        short8v vv = *(const short8v*)(QKVG + (size_t)(tok0 + t) * NPROJ + 1024 + h * 256 + 128 + jg * 8);
        #pragma unroll
        for (int e = 0; e < 8; e++)
            VT[sw8(jg * 8 + e, t)] = (unsigned short)vv[e];
    }
    __syncthreads();
    {
        f32x4 uacc[8];
        #pragma unroll
        for (int jt = 0; jt < 8; jt++) uacc[jt] = (f32x4){0.f, 0.f, 0.f, 0.f};
        #pragma unroll
        for (int ks = 0; ks < 2; ks++) {
            short8v at = *(const short8v*)(Tb + sw8(16 * wv + fr, 32 * ks + 8 * fq));
            #pragma unroll
            for (int jt = 0; jt < 8; jt++) {
                short8v bv = *(const short8v*)(VT + sw8(16 * jt + fr, 32 * ks + 8 * fq));
                uacc[jt] = __builtin_amdgcn_mfma_f32_16x16x32_bf16(at, bv, uacc[jt], 0, 0, 0);
            }
        }
        #pragma unroll
        for (int jt = 0; jt < 8; jt++)
            #pragma unroll
            for (int r = 0; r < 4; r++) {
                int t = 16 * wv + 4 * fq + r, j = 16 * jt + fr;
                Ubuf[cb * 16384 + (size_t)t * 256 + 128 + j] = f2bf(uacc[jt][r]);
            }
    }
}

// ---------------- MFMA chunk scan ----------------
// grid (4 dv-slices, 8 bh), 256 threads. State S[128][64] f32 in MFMA accumulators.
// LDS (2B elems): dbuf { W 8192 | Q 8192 | KT 8192 | P 4096 | U 4096 } = 32768 x2,
// then ST 8192, DT 4096. Total 77824 elems = 155648 B.
#define SBUF   32768
#define SW_OFF 0
#define SQ_OFF 8192
#define SKT_OFF 16384
#define SP_OFF 24576
#define SU_OFF 28672
#define SST_OFF (2 * SBUF)
#define SDT_OFF (2 * SBUF + 8192)

__global__ __launch_bounds__(256, 1) void scan_mfma(
    const unsigned short* __restrict__ QKVG, const unsigned short* __restrict__ Wbuf,
    const unsigned short* __restrict__ Ubuf, const unsigned short* __restrict__ Pbuf,
    const unsigned short* __restrict__ KTbuf, unsigned short* __restrict__ Ob)
{
    extern __shared__ unsigned short lds[];
    int tid = threadIdx.x;
    int wv = tid >> 6, ln = tid & 63;
    int fr = ln & 15, fq = ln >> 4;
    int j0 = blockIdx.x * 64;
    int bh = blockIdx.y;
    int b = bh >> 2, h = bh & 3;

    unsigned short* ST = lds + SST_OFF;
    unsigned short* DT = lds + SDT_OFF;

    // shifted-identity B-fragments: id_s[n][k] = (k == n + 16*s)
    short8v id0, id1;
    #pragma unroll
    for (int e = 0; e < 8; e++) {
        id0[e] = (short)((8 * fq + e == fr) ? 0x3F80 : 0);
        id1[e] = (short)((8 * fq + e == fr + 16) ? 0x3F80 : 0);
    }

    f32x4 sacc[2][4];
    #pragma unroll
    for (int i = 0; i < 2; i++)
        #pragma unroll
        for (int j = 0; j < 4; j++) sacc[i][j] = (f32x4){0.f, 0.f, 0.f, 0.f};

    short8v rg[16];
    auto issue = [&](int c1) {
        size_t cb = (size_t)bh * NCHUNK + c1;
        const unsigned short* Wc = Wbuf + cb * (64 * 128);
        const unsigned short* Uc = Ubuf + cb * (64 * 256);
        const unsigned short* Pc = Pbuf + cb * (64 * 64);
        const unsigned short* Kc = KTbuf + cb * (128 * 64);
        int tok0 = b * SEQ + c1 * 64;
        #pragma unroll
        for (int i = 0; i < 4; i++) {
            int p = tid + 256 * i;
            int t = p >> 4, up = p & 15;
            int u = (up & 8) | ((up ^ t) & 7);
            rg[i] = *(const short8v*)(Wc + t * 128 + u * 8);
            rg[4 + i] = *(const short8v*)(QKVG + (size_t)(tok0 + t) * NPROJ + h * 128 + u * 8);
            int d = p >> 3;
            int u8 = (p ^ d) & 7;
            rg[8 + i] = *(const short8v*)(Kc + d * 64 + u8 * 8);
        }
        #pragma unroll
        for (int i = 0; i < 2; i++) {
            int p = tid + 256 * i;
            int t = p >> 3;
            int u8 = (p ^ t) & 7;
            rg[12 + i] = *(const short8v*)(Pc + t * 64 + u8 * 8);
            rg[14 + i] = *(const short8v*)(Uc + t * 256 + j0 + (p & 7) * 8);
        }
    };
    auto commit = [&](unsigned short* bb) {
        #pragma unroll
        for (int i = 0; i < 4; i++) {
            int p = tid + 256 * i;
            *(short8v*)(bb + SW_OFF + p * 8) = rg[i];
            *(short8v*)(bb + SQ_OFF + p * 8) = rg[4 + i];
            *(short8v*)(bb + SKT_OFF + p * 8) = rg[8 + i];
        }
        #pragma unroll
        for (int i = 0; i < 2; i++) {
            int p = tid + 256 * i;
            int t = p >> 3;
            *(short8v*)(bb + SP_OFF + p * 8) = rg[12 + i];
            *(short8v*)(bb + SU_OFF + sw8(t, (p & 7) * 8)) = rg[14 + i];
        }
    };

    issue(0);
    commit(lds);
    __syncthreads();   // initial full drain (once)

    for (int c = 0; c < NCHUNK; c++) {
        unsigned short* ba = (c & 1) ? (lds + SBUF) : lds;
        unsigned short* bb = (c & 1) ? lds : (lds + SBUF);

        // A: dump state S -> ST[j][d] bf16 (swizzled)
        #pragma unroll
        for (int dtt = 0; dtt < 2; dtt++)
            #pragma unroll
            for (int jt = 0; jt < 4; jt++) {
                int d0 = 32 * wv + 16 * dtt + 4 * fq;
                int j = 16 * jt + fr;
                f32x4 v = sacc[dtt][jt];
                unsigned int lo = f2bf(v[0]) | ((unsigned)f2bf(v[1]) << 16);
                unsigned int hi = f2bf(v[2]) | ((unsigned)f2bf(v[3]) << 16);
                *(uint2*)&ST[sw16(j, d0)] = make_uint2(lo, hi);
            }
        if (c < NCHUNK - 1) issue(c + 1);   // prefetch stays in flight across barriers
        bar_lgkm();

        // B: dacc = (-W)*S, oacc = Q*S; then Delta = U + dacc via identity-MFMA
        f32x4 dacc[4], oacc[4];
        #pragma unroll
        for (int jt = 0; jt < 4; jt++) {
            dacc[jt] = (f32x4){0.f, 0.f, 0.f, 0.f};
            oacc[jt] = (f32x4){0.f, 0.f, 0.f, 0.f};
        }
        #pragma unroll
        for (int ks = 0; ks < 4; ks++) {
            short8v aw = *(const short8v*)(ba + SW_OFF + sw16(16 * wv + fr, 32 * ks + 8 * fq));
            short8v aq = *(const short8v*)(ba + SQ_OFF + sw16(16 * wv + fr, 32 * ks + 8 * fq));
            #pragma unroll
            for (int jt = 0; jt < 4; jt++) {
                short8v bs = *(const short8v*)(ST + sw16(16 * jt + fr, 32 * ks + 8 * fq));
                dacc[jt] = __builtin_amdgcn_mfma_f32_16x16x32_bf16(aw, bs, dacc[jt], 0, 0, 0);
                oacc[jt] = __builtin_amdgcn_mfma_f32_16x16x32_bf16(aq, bs, oacc[jt], 0, 0, 0);
            }
        }
        #pragma unroll
        for (int jt2 = 0; jt2 < 2; jt2++) {
            short8v au = *(const short8v*)(ba + SU_OFF + sw8(16 * wv + fr, 32 * jt2 + 8 * fq));
            dacc[2 * jt2 + 0] = __builtin_amdgcn_mfma_f32_16x16x32_bf16(au, id0, dacc[2 * jt2 + 0], 0, 0, 0);
            dacc[2 * jt2 + 1] = __builtin_amdgcn_mfma_f32_16x16x32_bf16(au, id1, dacc[2 * jt2 + 1], 0, 0, 0);
        }
        #pragma unroll
        for (int jt = 0; jt < 4; jt++) oacc[jt] *= SCQ;
        // Delta (=dacc) -> DT[j][t] bf16 (swizzled transpose)
        #pragma unroll
        for (int jt = 0; jt < 4; jt++) {
            int j = 16 * jt + fr;
            int t0 = 16 * wv + 4 * fq;
            unsigned int lo = f2bf(dacc[jt][0]) | ((unsigned)f2bf(dacc[jt][1]) << 16);
            unsigned int hi = f2bf(dacc[jt][2]) | ((unsigned)f2bf(dacc[jt][3]) << 16);
            *(uint2*)&DT[sw8(j, t0)] = make_uint2(lo, hi);
        }
        bar_lgkm();

        // C: oacc += P * Delta ; S += K^T * Delta ; O stores ; commit next buffer
        #pragma unroll
        for (int ks = 0; ks < 2; ks++) {
            short8v ap = *(const short8v*)(ba + SP_OFF + sw8(16 * wv + fr, 32 * ks + 8 * fq));
            #pragma unroll
            for (int jt = 0; jt < 4; jt++) {
                short8v bd = *(const short8v*)(DT + sw8(16 * jt + fr, 32 * ks + 8 * fq));
                oacc[jt] = __builtin_amdgcn_mfma_f32_16x16x32_bf16(ap, bd, oacc[jt], 0, 0, 0);
            }
        }
        #pragma unroll
        for (int ks = 0; ks < 2; ks++) {
            short8v ak0 = *(const short8v*)(ba + SKT_OFF + sw8(32 * wv + fr, 32 * ks + 8 * fq));
            short8v ak1 = *(const short8v*)(ba + SKT_OFF + sw8(32 * wv + 16 + fr, 32 * ks + 8 * fq));
            #pragma unroll
            for (int jt = 0; jt < 4; jt++) {
                short8v bd = *(const short8v*)(DT + sw8(16 * jt + fr, 32 * ks + 8 * fq));
                sacc[0][jt] = __builtin_amdgcn_mfma_f32_16x16x32_bf16(ak0, bd, sacc[0][jt], 0, 0, 0);
                sacc[1][jt] = __builtin_amdgcn_mfma_f32_16x16x32_bf16(ak1, bd, sacc[1][jt], 0, 0, 0);
            }
        }
        int tok0 = b * SEQ + c * 64;
        #pragma unroll
        for (int jt = 0; jt < 4; jt++)
            #pragma unroll
            for (int r = 0; r < 4; r++) {
                int t = 16 * wv + 4 * fq + r;
                Ob[(size_t)(tok0 + t) * 1024 + h * 256 + j0 + 16 * jt + fr] = f2bf(oacc[jt][r]);
            }
        if (c < NCHUNK - 1) commit(bb);   // compiler inserts counted vmcnt for rg deps
        bar_lgkm();
    }
}

// ---------------- RMSNorm + swish gate ----------------
__global__ void gate_norm(const unsigned short* __restrict__ Ob,
                          const unsigned short* __restrict__ QKVG,
                          const float* __restrict__ norm_w,
                          unsigned short* __restrict__ o2)
{
    __shared__ float red[4];
    int tok = blockIdx.x >> 2, h = blockIdx.x & 3;
    int j = threadIdx.x;
    float o = bf2f(Ob[(size_t)tok * 1024 + h * 256 + j]);
    float ss = o * o;
    #pragma unroll
    for (int off = 32; off; off >>= 1) ss += __shfl_xor(ss, off);
    if ((threadIdx.x & 63) == 0) red[threadIdx.x >> 6] = ss;
    __syncthreads();
    float tot = red[0] + red[1] + red[2] + red[3];
    float r = rsqrtf(tot * (1.0f / 256.0f) + 1e-5f);
    float g = bf2f(QKVG[(size_t)tok * NPROJ + 2048 + h * 256 + j]);
    float sw = g / (1.f + __expf(-g));
    o2[(size_t)tok * 1024 + h * 256 + j] = f2bf(o * r * norm_w[j] * sw);
}

// ---------------- launch ----------------
extern "C" void kernel_launch(void* const* d_in, const int* in_sizes, int n_in,
                              void* d_out, int out_size, void* d_ws, size_t ws_size,
                              hipStream_t stream) {
    const float* x      = (const float*)d_in[0];
    const float* Wq     = (const float*)d_in[1];
    const float* Wk     = (const float*)d_in[2];
    const float* Wv     = (const float*)d_in[3];
    const float* Wb     = (const float*)d_in[4];
    const float* Wg     = (const float*)d_in[5];
    const float* Wo     = (const float*)d_in[6];
    const float* norm_w = (const float*)d_in[7];
    float* out = (float*)d_out;

    char* ws = (char*)d_ws;
    unsigned short* xb   = (unsigned short*)(ws + 0);          // 16,777,216
    unsigned short* KTbuf= (unsigned short*)(ws + 0);          // aliases xb (dead after gemm<0>)
    unsigned short* WT   = (unsigned short*)(ws + 16777216);   //  6,291,456
    unsigned short* WoT  = (unsigned short*)(ws + 23068672);   //  2,097,152
    unsigned short* QKVG = (unsigned short*)(ws + 25165824);   // 50,331,648
    float*          beta = (float*)        (ws + 75497472);    //    131,072
    unsigned short* Wbuf = (unsigned short*)(ws + 75628544);   //  8,388,608
    unsigned short* Ubuf = (unsigned short*)(ws + 84017152);   // 16,777,216
    unsigned short* Pbuf = (unsigned short*)(ws + 100794368);  //  4,194,304
    unsigned short* Ob   = (unsigned short*)(ws + 104988672);  // 16,777,216
    unsigned short* o2   = (unsigned short*)(ws + 121765888);  // 16,777,216

    (void)hipFuncSetAttribute((const void*)scan_mfma,
                              hipFuncAttributeMaxDynamicSharedMemorySize, 155648);

    convert_x<<<(NTOK * DM + 255) / 256, 256, 0, stream>>>(x, xb, NTOK * DM);
    build_wt<<<(NPROJ * DM + 255) / 256, 256, 0, stream>>>(Wq, Wk, Wv, Wg, WT);
    build_wot<<<(DM * DM + 255) / 256, 256, 0, stream>>>(Wo, WoT);
    beta_kernel<<<NTOK / 16, 256, 0, stream>>>(x, Wb, beta);
    gemm_bt<0><<<dim3(64, 24), 256, 0, stream>>>(xb, WT, (void*)QKVG, NTOK, NPROJ, DM);
    chunk_pre<<<dim3(NCHUNK, 8), 256, 0, stream>>>(QKVG, beta, Wbuf, Ubuf, Pbuf, KTbuf);
    scan_mfma<<<dim3(4, 8), 256, 155648, stream>>>(QKVG, Wbuf, Ubuf, Pbuf, KTbuf, Ob);
    gate_norm<<<NTOK * 4, 256, 0, stream>>>(Ob, QKVG, norm_w, o2);
    gemm_bt<1><<<dim3(64, 8), 256, 0, stream>>>(o2, WoT, (void*)out, NTOK, DM, DM);
}